// Round 1
// baseline (12387.638 us; speedup 1.0000x reference)
//
#include <hip/hip_runtime.h>

// RecurrentTransformerEncoder on MI355X — fp32 correctness-first baseline.
// B=64, T=16, SEG=50, E=D=512, H=8, DH=64, F=2048.
// Phase 1: all 16 encoders batched (chunks of G=4 segments, M=12800).
// Phase 2: 15 sequential connection steps (M=3200).
// Workspace ≈ 348 MB fp32.

#define NB   64      // batch
#define NT   16      // segments
#define SEGL 50
#define DMODEL 512
#define DFF  2048
#define NHEAD 8
#define DHEAD 64

// ---------------------------------------------------------------------------
// SGEMM: C[M,N] = op(A[M,K] @ B[K,N]); A rows remapped via (agrp, astride):
// row m lives at A + (m/agrp)*astride + (m%agrp)*K. Packed A: agrp=M, astride=0.
// relu!=0 applies max(0,x) epilogue. Requires M%BM==0, N%BN==0, K%BK==0.
// ---------------------------------------------------------------------------
template<int BM, int BN, int BK, int TM, int TN>
__global__ __launch_bounds__(256) void sgemm_k(
    const float* __restrict__ A, int agrp, long long astride,
    const float* __restrict__ B, float* __restrict__ C,
    int M, int N, int K, int relu)
{
    __shared__ float As[BK][BM];
    __shared__ float Bs[BK][BN];
    const int tid = threadIdx.x;
    const int bm = blockIdx.y * BM;
    const int bn = blockIdx.x * BN;
    constexpr int NTN = BN / TN;           // threads along N
    const int tn = tid % NTN;
    const int tm = tid / NTN;
    float acc[TM][TN];
#pragma unroll
    for (int i = 0; i < TM; ++i)
#pragma unroll
        for (int j = 0; j < TN; ++j) acc[i][j] = 0.f;

    constexpr int ACG = BK / 4;            // float4 col-groups in A tile
    const int arow = tid / ACG;
    const int acol = (tid % ACG) * 4;
    constexpr int BCG = BN / 4;
    const int brow = tid / BCG;
    const int bcol = (tid % BCG) * 4;

    const int am = bm + arow;
    const float* Arow = A + (long long)(am / agrp) * astride + (long long)(am % agrp) * K;

    for (int kk = 0; kk < K; kk += BK) {
        float4 av = *(const float4*)(Arow + kk + acol);
        float4 bv = *(const float4*)(B + (long long)(kk + brow) * N + bn + bcol);
        As[acol + 0][arow] = av.x;
        As[acol + 1][arow] = av.y;
        As[acol + 2][arow] = av.z;
        As[acol + 3][arow] = av.w;
        *(float4*)&Bs[brow][bcol] = bv;
        __syncthreads();
#pragma unroll
        for (int k = 0; k < BK; ++k) {
            float a[TM], b[TN];
#pragma unroll
            for (int i = 0; i < TM; i += 4) *(float4*)&a[i] = *(const float4*)&As[k][tm * TM + i];
#pragma unroll
            for (int j = 0; j < TN; j += 4) *(float4*)&b[j] = *(const float4*)&Bs[k][tn * TN + j];
#pragma unroll
            for (int i = 0; i < TM; ++i)
#pragma unroll
                for (int j = 0; j < TN; ++j) acc[i][j] = fmaf(a[i], b[j], acc[i][j]);
        }
        __syncthreads();
    }
#pragma unroll
    for (int i = 0; i < TM; ++i) {
        float* Cp = C + (long long)(bm + tm * TM + i) * N + bn + tn * TN;
#pragma unroll
        for (int j = 0; j < TN; j += 4) {
            float4 v;
            v.x = acc[i][j]; v.y = acc[i][j + 1]; v.z = acc[i][j + 2]; v.w = acc[i][j + 3];
            if (relu) {
                v.x = fmaxf(v.x, 0.f); v.y = fmaxf(v.y, 0.f);
                v.z = fmaxf(v.z, 0.f); v.w = fmaxf(v.w, 0.f);
            }
            *(float4*)(Cp + j) = v;
        }
    }
}

// ---------------------------------------------------------------------------
// Attention for one (sequence, head): sq=sk=50, dh=64; packed Q/K/V/O rows
// (seq n occupies rows n*50..n*50+49, row stride 512, head h at cols h*64..).
// lens==nullptr → len=50 (full). Else seq n maps to (b = n/G, t = t0 + n%G),
// len = lens[b*NT + t]. Mask value -1e9 matches reference exactly.
// ---------------------------------------------------------------------------
__global__ __launch_bounds__(256) void attn_k(
    const float* __restrict__ Q, const float* __restrict__ K,
    const float* __restrict__ V, float* __restrict__ O,
    const int* __restrict__ lens, int G, int t0)
{
    __shared__ float qs[SEGL][DHEAD];
    __shared__ float ks[SEGL][DHEAD];
    __shared__ float vs[SEGL][DHEAD];
    __shared__ float sc[SEGL][SEGL];
    const int n = blockIdx.x >> 3;
    const int h = blockIdx.x & 7;
    const int tid = threadIdx.x;
    int len = SEGL;
    if (lens) {
        int b = n / G;
        int t = t0 + (n % G);
        len = lens[b * NT + t];
        if (len > SEGL) len = SEGL;
    }
    // cooperative load: 800 float4 per matrix
    for (int idx = tid; idx < SEGL * (DHEAD / 4); idx += 256) {
        int s = idx >> 4, d4 = (idx & 15) << 2;
        long long off = ((long long)(n * SEGL + s)) * DMODEL + h * DHEAD + d4;
        *(float4*)&qs[s][d4] = *(const float4*)(Q + off);
        *(float4*)&ks[s][d4] = *(const float4*)(K + off);
        *(float4*)&vs[s][d4] = *(const float4*)(V + off);
    }
    __syncthreads();
    // scores
    for (int idx = tid; idx < SEGL * SEGL; idx += 256) {
        int i = idx / SEGL, j = idx % SEGL;
        float dot = 0.f;
#pragma unroll
        for (int d = 0; d < DHEAD; d += 4) {
            float4 qv = *(const float4*)&qs[i][d];
            float4 kv = *(const float4*)&ks[j][d];
            dot = fmaf(qv.x, kv.x, dot);
            dot = fmaf(qv.y, kv.y, dot);
            dot = fmaf(qv.z, kv.z, dot);
            dot = fmaf(qv.w, kv.w, dot);
        }
        sc[i][j] = (j < len) ? dot * 0.125f : -1e9f;
    }
    __syncthreads();
    // softmax per query row (one wave per row)
    const int wave = tid >> 6, lane = tid & 63;
    for (int r = wave; r < SEGL; r += 4) {
        float x = (lane < SEGL) ? sc[r][lane] : -1e30f;
        float m = x;
        for (int off = 32; off; off >>= 1) m = fmaxf(m, __shfl_xor(m, off));
        float e = (lane < SEGL) ? __expf(x - m) : 0.f;
        float ssum = e;
        for (int off = 32; off; off >>= 1) ssum += __shfl_xor(ssum, off);
        if (lane < SEGL) sc[r][lane] = e / ssum;
    }
    __syncthreads();
    // O = P @ V
    for (int idx = tid; idx < SEGL * DHEAD; idx += 256) {
        int s = idx >> 6, d = idx & 63;
        float a = 0.f;
#pragma unroll 10
        for (int j = 0; j < SEGL; ++j) a = fmaf(sc[s][j], vs[j][d], a);
        O[((long long)(n * SEGL + s)) * DMODEL + h * DHEAD + d] = a;
    }
}

// ---------------------------------------------------------------------------
// out = LN(a + b) * gamma + beta, rows of 512. One wave per row, 8 elems/lane.
// a and out use (grp, stride) row remapping (same convention as sgemm A).
// ---------------------------------------------------------------------------
__global__ __launch_bounds__(256) void add_ln_k(
    const float* __restrict__ A, int agrp, long long astride,
    const float* __restrict__ Bv,
    const float* __restrict__ gamma, const float* __restrict__ beta,
    float* __restrict__ O, int ogrp, long long ostride, int M)
{
    const int wave = threadIdx.x >> 6, lane = threadIdx.x & 63;
    const int r = blockIdx.x * 4 + wave;
    if (r >= M) return;
    const float* a = A + (long long)(r / agrp) * astride + (long long)(r % agrp) * DMODEL;
    const float* b = Bv + (long long)r * DMODEL;
    float* o = O + (long long)(r / ogrp) * ostride + (long long)(r % ogrp) * DMODEL;
    float x[8];
    {
        float4 a0 = *(const float4*)(a + lane * 8);
        float4 a1 = *(const float4*)(a + lane * 8 + 4);
        float4 b0 = *(const float4*)(b + lane * 8);
        float4 b1 = *(const float4*)(b + lane * 8 + 4);
        x[0] = a0.x + b0.x; x[1] = a0.y + b0.y; x[2] = a0.z + b0.z; x[3] = a0.w + b0.w;
        x[4] = a1.x + b1.x; x[5] = a1.y + b1.y; x[6] = a1.z + b1.z; x[7] = a1.w + b1.w;
    }
    float s = 0.f, s2 = 0.f;
#pragma unroll
    for (int i = 0; i < 8; ++i) { s += x[i]; s2 = fmaf(x[i], x[i], s2); }
    for (int off = 32; off; off >>= 1) {
        s += __shfl_xor(s, off);
        s2 += __shfl_xor(s2, off);
    }
    const float mean = s * (1.f / DMODEL);
    const float var = s2 * (1.f / DMODEL) - mean * mean;
    const float inv = rsqrtf(var + 1e-5f);
    float4 g0 = *(const float4*)(gamma + lane * 8);
    float4 g1 = *(const float4*)(gamma + lane * 8 + 4);
    float4 be0 = *(const float4*)(beta + lane * 8);
    float4 be1 = *(const float4*)(beta + lane * 8 + 4);
    float4 y0, y1;
    y0.x = (x[0] - mean) * inv * g0.x + be0.x;
    y0.y = (x[1] - mean) * inv * g0.y + be0.y;
    y0.z = (x[2] - mean) * inv * g0.z + be0.z;
    y0.w = (x[3] - mean) * inv * g0.w + be0.w;
    y1.x = (x[4] - mean) * inv * g1.x + be1.x;
    y1.y = (x[5] - mean) * inv * g1.y + be1.y;
    y1.z = (x[6] - mean) * inv * g1.z + be1.z;
    y1.w = (x[7] - mean) * inv * g1.w + be1.w;
    *(float4*)(o + lane * 8) = y0;
    *(float4*)(o + lane * 8 + 4) = y1;
}

// lens[b*NT + t] = min(ends[b,t] - ends[b,t-1], 50) (t=0: min(ends[b,0],50))
__global__ void lens_k(const int* __restrict__ ends, int* __restrict__ lens)
{
    int i = blockIdx.x * 256 + threadIdx.x;
    if (i >= NB * NT) return;
    int t = i & (NT - 1);
    int prev = t ? ends[i - 1] : 0;
    int l = ends[i] - prev;
    if (l > SEGL) l = SEGL;
    lens[i] = l;
}

// ---------------------------------------------------------------------------
extern "C" void kernel_launch(void* const* d_in, const int* in_sizes, int n_in,
                              void* d_out, int out_size, void* d_ws, size_t ws_size,
                              hipStream_t stream)
{
    const float* seqs = (const float*)d_in[0];
    const int*   ends = (const int*)d_in[1];
    const float* eWin = (const float*)d_in[2];
    const float* eWq  = (const float*)d_in[3];
    const float* eWk  = (const float*)d_in[4];
    const float* eWv  = (const float*)d_in[5];
    const float* eWo  = (const float*)d_in[6];
    const float* eG1  = (const float*)d_in[7];
    const float* eB1  = (const float*)d_in[8];
    const float* eF1  = (const float*)d_in[9];
    const float* eF2  = (const float*)d_in[10];
    const float* eG2  = (const float*)d_in[11];
    const float* eB2  = (const float*)d_in[12];
    const float* cWq  = (const float*)d_in[13];
    const float* cWk  = (const float*)d_in[14];
    const float* cWv  = (const float*)d_in[15];
    const float* cWo  = (const float*)d_in[16];
    const float* cG1  = (const float*)d_in[17];
    const float* cB1  = (const float*)d_in[18];
    const float* cF1  = (const float*)d_in[19];
    const float* cF2  = (const float*)d_in[20];
    const float* cG2  = (const float*)d_in[21];
    const float* cB2  = (const float*)d_in[22];
    float* out = (float*)d_out;

    // workspace layout (fp32 elems); total ≈ 86.8M floats ≈ 348 MB
    float* ws = (float*)d_ws;
    const long long SEQROW = (long long)NT * SEGL * DMODEL;   // 409600: b-stride in rows*512
    float* ENC  = ws;                               // 51200*512
    float* BUF0 = ENC  + (long long)51200 * 512;    // 12800*512 each
    float* BUF1 = BUF0 + (long long)12800 * 512;
    float* BUF2 = BUF1 + (long long)12800 * 512;
    float* BUF3 = BUF2 + (long long)12800 * 512;
    float* BUF4 = BUF3 + (long long)12800 * 512;
    float* MID  = BUF4 + (long long)12800 * 512;    // 12800*2048
    float* OUTB = MID  + (long long)12800 * 2048;   // 3200*512
    int*   lens = (int*)(OUTB + (long long)3200 * 512);

    lens_k<<<4, 256, 0, stream>>>(ends, lens);

    auto gemm128 = [&](const float* A, int agrp, long long astr, const float* B,
                       float* C, int M, int N, int K, int relu) {
        dim3 g(N / 128, M / 128);
        sgemm_k<128, 128, 8, 8, 8><<<g, 256, 0, stream>>>(A, agrp, astr, B, C, M, N, K, relu);
    };
    auto gemm64 = [&](const float* A, int agrp, long long astr, const float* B,
                      float* C, int M, int N, int K, int relu) {
        dim3 g(N / 64, M / 64);
        sgemm_k<64, 64, 16, 4, 4><<<g, 256, 0, stream>>>(A, agrp, astr, B, C, M, N, K, relu);
    };

    // ---------------- Phase 1: all encoders, chunks of G=4 segments ----------
    const int G = 4;
    const int Mc = NB * G * SEGL;   // 12800
    for (int c = 0; c < NT / G; ++c) {
        const int t0 = c * G;
        const float* Abase = seqs + (long long)t0 * SEGL * DMODEL;
        float* ENCc = ENC + (long long)t0 * SEGL * DMODEL;
        // h0 = x @ eWin
        gemm128(Abase, G * SEGL, SEQROW * 1LL, eWin, BUF0, Mc, 512, 512, 0);
        // q,k,v
        gemm128(BUF0, Mc, 0, eWq, BUF1, Mc, 512, 512, 0);
        gemm128(BUF0, Mc, 0, eWk, BUF2, Mc, 512, 512, 0);
        gemm128(BUF0, Mc, 0, eWv, BUF3, Mc, 512, 512, 0);
        // attention (masked by seg lens)
        attn_k<<<NB * G * NHEAD, 256, 0, stream>>>(BUF1, BUF2, BUF3, BUF4, lens, G, t0);
        // attn_out @ eWo  -> BUF1
        gemm128(BUF4, Mc, 0, eWo, BUF1, Mc, 512, 512, 0);
        // h1 = LN(h0 + attnproj) -> BUF2
        add_ln_k<<<Mc / 4, 256, 0, stream>>>(BUF0, Mc, 0, BUF1, eG1, eB1, BUF2, Mc, 0, Mc);
        // ffn
        gemm128(BUF2, Mc, 0, eF1, MID, Mc, 2048, 512, 1);
        gemm128(MID, Mc, 0, eF2, BUF3, Mc, 512, 2048, 0);
        // enc = LN(h1 + ffn) -> ENC (grouped write)
        add_ln_k<<<Mc / 4, 256, 0, stream>>>(BUF2, Mc, 0, BUF3, eG2, eB2, ENCc, G * SEGL, SEQROW, Mc);
    }

    // ---------------- Phase 2: 15 sequential connection steps ----------------
    const int Ms = NB * SEGL;   // 3200
    for (int t = 1; t < NT; ++t) {
        const float* currA = ENC + (long long)t * SEGL * DMODEL;  // grouped (50, SEQROW)
        const float* prevA; int pg; long long ps;
        if (t == 1) { prevA = ENC;  pg = SEGL; ps = SEQROW; }
        else        { prevA = OUTB; pg = Ms;   ps = 0; }
        gemm64(currA, SEGL, SEQROW, cWq, BUF1, Ms, 512, 512, 0);
        gemm64(prevA, pg, ps,       cWk, BUF2, Ms, 512, 512, 0);
        gemm64(prevA, pg, ps,       cWv, BUF3, Ms, 512, 512, 0);
        attn_k<<<NB * NHEAD, 256, 0, stream>>>(BUF1, BUF2, BUF3, BUF4, nullptr, 1, 0);
        gemm64(BUF4, Ms, 0, cWo, BUF0, Ms, 512, 512, 0);
        // h = LN(curr + attnproj) -> BUF1
        add_ln_k<<<Ms / 4, 256, 0, stream>>>(currA, SEGL, SEQROW, BUF0, cG1, cB1, BUF1, Ms, 0, Ms);
        gemm64(BUF1, Ms, 0, cF1, MID, Ms, 2048, 512, 1);
        gemm64(MID, Ms, 0, cF2, BUF0, Ms, 512, 2048, 0);
        float* dst = (t == NT - 1) ? out : OUTB;
        add_ln_k<<<Ms / 4, 256, 0, stream>>>(BUF1, Ms, 0, BUF0, cG2, cB2, dst, Ms, 0, Ms);
    }
}

// Round 2
// 5065.902 us; speedup vs baseline: 2.4453x; 2.4453x over previous
//
#include <hip/hip_runtime.h>

// RecurrentTransformerEncoder on MI355X — round 2: bf16 MFMA GEMMs.
// B=64, T=16, SEG=50, E=D=512, H=8, DH=64, F=2048.
// All GEMM B-operands are weights -> pre-transposed to Wt[N][K] bf16.
// Activations bf16 throughout; LN/softmax stats fp32; final output fp32.

#define NB   64
#define NT   16
#define SEGL 50
#define DMODEL 512
#define DFF  2048
#define NHEAD 8
#define DHEAD 64

typedef unsigned short ushort_t;
typedef __attribute__((ext_vector_type(8))) short bfrag;   // 8 bf16 (4 VGPRs)
typedef __attribute__((ext_vector_type(4))) float ffrag;   // 4 fp32 acc

__device__ __forceinline__ ushort_t f2b(float x) {
    union { float f; unsigned u; } c; c.f = x;
    unsigned r = c.u + 0x7fffu + ((c.u >> 16) & 1u);
    return (ushort_t)(r >> 16);
}
__device__ __forceinline__ float b2f(ushort_t x) {
    union { unsigned u; float f; } c; c.u = ((unsigned)x) << 16;
    return c.f;
}

#define GLOAD_LDS16(g, l) __builtin_amdgcn_global_load_lds( \
    (const __attribute__((address_space(1))) void*)(g),      \
    (__attribute__((address_space(3))) void*)(l), 16, 0, 0)

// ---------------------------------------------------------------------------
// MFMA GEMM: C[M,N](bf16) = relu?(A[M,K](bf16) @ Bt[N,K](bf16)^T)
// A rows remapped: row m at A + (m/agrp)*astride + (m%agrp)*K.
// 256 threads = 4 waves arranged WROWS x WCOLS. mfma_f32_16x16x32_bf16.
// LDS in fragment order: subtile = 16 rows x 32 k = 64 lanes x 16B; lane l's
// chunk = [row s*16+(l&15)][k (l>>4)*8 .. +7], staged by global_load_lds so
// data lands at base + l*16 (wave-uniform base, per-lane global addr).
// ---------------------------------------------------------------------------
template<int BM, int BN, int WROWS, int WCOLS>
__global__ __launch_bounds__(256) void mfma_gemm(
    const ushort_t* __restrict__ A, int agrp, long long astride,
    const ushort_t* __restrict__ Bt, ushort_t* __restrict__ C,
    int M, int N, int K, int relu)
{
    constexpr int WM = BM / WROWS, WN = BN / WCOLS;
    constexpr int SM = WM / 16, SN = WN / 16;
    constexpr int NSUBA = BM / 16, NSUBB = BN / 16;
    constexpr int NSUB = NSUBA + NSUBB;
    constexpr int SPW = NSUB / 4;            // subtile stage-loads per wave
    __shared__ ushort_t lds[NSUB * 512];     // 1 KB per subtile

    const int tid = threadIdx.x;
    const int wave = tid >> 6, lane = tid & 63;
    const int wrow = wave / WCOLS, wcol = wave % WCOLS;
    const int bm = blockIdx.y * BM, bn = blockIdx.x * BN;
    const int lm = lane & 15, lq = lane >> 4;

    ffrag acc[SM][SN];
#pragma unroll
    for (int i = 0; i < SM; ++i)
#pragma unroll
        for (int j = 0; j < SN; ++j) acc[i][j] = (ffrag){0.f, 0.f, 0.f, 0.f};

    const ushort_t* gptr[SPW];
    ushort_t* lptr[SPW];
#pragma unroll
    for (int i = 0; i < SPW; ++i) {
        int s = wave * SPW + i;
        if (s < NSUBA) {
            int m = bm + s * 16 + lm;
            gptr[i] = A + (long long)(m / agrp) * astride
                        + (long long)(m % agrp) * K + lq * 8;
        } else {
            int n = bn + (s - NSUBA) * 16 + lm;
            gptr[i] = Bt + (long long)n * K + lq * 8;
        }
        lptr[i] = &lds[s * 512];
    }

    for (int kk = 0; kk < K; kk += 32) {
        __syncthreads();
#pragma unroll
        for (int i = 0; i < SPW; ++i)
            GLOAD_LDS16(gptr[i] + kk, lptr[i]);
        __builtin_amdgcn_s_waitcnt(0);
        __syncthreads();

        bfrag af[SM], bfg[SN];
#pragma unroll
        for (int i = 0; i < SM; ++i)
            af[i] = *(const bfrag*)&lds[(wrow * SM + i) * 512 + lane * 8];
#pragma unroll
        for (int j = 0; j < SN; ++j)
            bfg[j] = *(const bfrag*)&lds[(NSUBA + wcol * SN + j) * 512 + lane * 8];
#pragma unroll
        for (int i = 0; i < SM; ++i)
#pragma unroll
            for (int j = 0; j < SN; ++j)
                acc[i][j] = __builtin_amdgcn_mfma_f32_16x16x32_bf16(
                    af[i], bfg[j], acc[i][j], 0, 0, 0);
    }

    // epilogue: D[row=(lane>>4)*4+reg][col=lane&15]  (m89/m91-verified)
#pragma unroll
    for (int i = 0; i < SM; ++i)
#pragma unroll
        for (int j = 0; j < SN; ++j) {
            int col = bn + wcol * WN + j * 16 + lm;
#pragma unroll
            for (int r = 0; r < 4; ++r) {
                int row = bm + wrow * WM + i * 16 + lq * 4 + r;
                float v = acc[i][j][r];
                if (relu) v = fmaxf(v, 0.f);
                C[(long long)row * N + col] = f2b(v);
            }
        }
}

// ---------------------------------------------------------------------------
// Weight transpose+convert: W[K][N] fp32 -> Wt[N][K] bf16. 32x32 LDS tiles.
// ---------------------------------------------------------------------------
__global__ __launch_bounds__(256) void wtrans_k(
    const float* __restrict__ W, ushort_t* __restrict__ Wt, int K, int N)
{
    __shared__ float t[32][33];
    const int bk = blockIdx.y * 32, bn = blockIdx.x * 32;
    const int tx = threadIdx.x & 31, ty = threadIdx.x >> 5;
    for (int i = ty; i < 32; i += 8)
        t[i][tx] = W[(long long)(bk + i) * N + bn + tx];
    __syncthreads();
    for (int i = ty; i < 32; i += 8)
        Wt[(long long)(bn + i) * K + bk + tx] = f2b(t[tx][i]);
}

// fp32 -> bf16 bulk convert (8 elems/thread)
__global__ __launch_bounds__(256) void cvt_k(
    const float* __restrict__ in, ushort_t* __restrict__ out, long long n)
{
    long long i = ((long long)blockIdx.x * 256 + threadIdx.x) * 8;
    if (i >= n) return;
    float4 a = *(const float4*)(in + i);
    float4 b = *(const float4*)(in + i + 4);
    ushort_t o[8] = {f2b(a.x), f2b(a.y), f2b(a.z), f2b(a.w),
                     f2b(b.x), f2b(b.y), f2b(b.z), f2b(b.w)};
    *(uint4*)(out + i) = *(const uint4*)o;
}

// ---------------------------------------------------------------------------
// Attention for one (sequence, head), bf16 I/O, fp32 compute. Same layout
// conventions as round 1 (packed rows of 512, head h at cols h*64).
// ---------------------------------------------------------------------------
__global__ __launch_bounds__(256) void attn_k(
    const ushort_t* __restrict__ Q, const ushort_t* __restrict__ K,
    const ushort_t* __restrict__ V, ushort_t* __restrict__ O,
    const int* __restrict__ lens, int G, int t0)
{
    __shared__ float qs[SEGL][DHEAD];
    __shared__ float ks[SEGL][DHEAD];
    __shared__ float vs[SEGL][DHEAD];
    __shared__ float sc[SEGL][SEGL];
    const int n = blockIdx.x >> 3;
    const int h = blockIdx.x & 7;
    const int tid = threadIdx.x;
    int len = SEGL;
    if (lens) {
        int b = n / G;
        int t = t0 + (n % G);
        len = lens[b * NT + t];
        if (len > SEGL) len = SEGL;
    }
    // load 50 rows x 8 chunks of 8 bf16 per matrix
    for (int idx = tid; idx < SEGL * 8; idx += 256) {
        int s = idx >> 3, d8 = (idx & 7) << 3;
        long long off = ((long long)(n * SEGL + s)) * DMODEL + h * DHEAD + d8;
        uint4 q4 = *(const uint4*)(Q + off);
        uint4 k4 = *(const uint4*)(K + off);
        uint4 v4 = *(const uint4*)(V + off);
        const unsigned* qa = (const unsigned*)&q4;
        const unsigned* ka = (const unsigned*)&k4;
        const unsigned* va = (const unsigned*)&v4;
#pragma unroll
        for (int c = 0; c < 4; ++c) {
            union { unsigned u; float f; } lo, hi;
            lo.u = qa[c] << 16; hi.u = qa[c] & 0xffff0000u;
            qs[s][d8 + 2 * c] = lo.f; qs[s][d8 + 2 * c + 1] = hi.f;
            lo.u = ka[c] << 16; hi.u = ka[c] & 0xffff0000u;
            ks[s][d8 + 2 * c] = lo.f; ks[s][d8 + 2 * c + 1] = hi.f;
            lo.u = va[c] << 16; hi.u = va[c] & 0xffff0000u;
            vs[s][d8 + 2 * c] = lo.f; vs[s][d8 + 2 * c + 1] = hi.f;
        }
    }
    __syncthreads();
    for (int idx = tid; idx < SEGL * SEGL; idx += 256) {
        int i = idx / SEGL, j = idx % SEGL;
        float dot = 0.f;
#pragma unroll
        for (int d = 0; d < DHEAD; d += 4) {
            float4 qv = *(const float4*)&qs[i][d];
            float4 kv = *(const float4*)&ks[j][d];
            dot = fmaf(qv.x, kv.x, dot);
            dot = fmaf(qv.y, kv.y, dot);
            dot = fmaf(qv.z, kv.z, dot);
            dot = fmaf(qv.w, kv.w, dot);
        }
        sc[i][j] = (j < len) ? dot * 0.125f : -1e9f;
    }
    __syncthreads();
    const int wave = tid >> 6, lane = tid & 63;
    for (int r = wave; r < SEGL; r += 4) {
        float x = (lane < SEGL) ? sc[r][lane] : -1e30f;
        float m = x;
        for (int off = 32; off; off >>= 1) m = fmaxf(m, __shfl_xor(m, off));
        float e = (lane < SEGL) ? __expf(x - m) : 0.f;
        float ssum = e;
        for (int off = 32; off; off >>= 1) ssum += __shfl_xor(ssum, off);
        if (lane < SEGL) sc[r][lane] = e / ssum;
    }
    __syncthreads();
    for (int idx = tid; idx < SEGL * DHEAD; idx += 256) {
        int s = idx >> 6, d = idx & 63;
        float a = 0.f;
#pragma unroll 10
        for (int j = 0; j < SEGL; ++j) a = fmaf(sc[s][j], vs[j][d], a);
        O[((long long)(n * SEGL + s)) * DMODEL + h * DHEAD + d] = f2b(a);
    }
}

// ---------------------------------------------------------------------------
// out = LN(a + b)*gamma + beta, rows of 512, bf16 inputs, bf16 or fp32 out.
// a and out use (grp, stride) row remapping (strides in elements).
// ---------------------------------------------------------------------------
template<bool OUTF32>
__global__ __launch_bounds__(256) void add_ln_k(
    const ushort_t* __restrict__ A, int agrp, long long astride,
    const ushort_t* __restrict__ Bv,
    const float* __restrict__ gamma, const float* __restrict__ beta,
    void* __restrict__ O, int ogrp, long long ostride, int M)
{
    const int wave = threadIdx.x >> 6, lane = threadIdx.x & 63;
    const int r = blockIdx.x * 4 + wave;
    if (r >= M) return;
    const ushort_t* a = A + (long long)(r / agrp) * astride + (long long)(r % agrp) * DMODEL;
    const ushort_t* b = Bv + (long long)r * DMODEL;
    float x[8];
    {
        uint4 a4 = *(const uint4*)(a + lane * 8);
        uint4 b4 = *(const uint4*)(b + lane * 8);
        const unsigned* aa = (const unsigned*)&a4;
        const unsigned* bb = (const unsigned*)&b4;
#pragma unroll
        for (int c = 0; c < 4; ++c) {
            union { unsigned u; float f; } alo, ahi, blo, bhi;
            alo.u = aa[c] << 16; ahi.u = aa[c] & 0xffff0000u;
            blo.u = bb[c] << 16; bhi.u = bb[c] & 0xffff0000u;
            x[2 * c]     = alo.f + blo.f;
            x[2 * c + 1] = ahi.f + bhi.f;
        }
    }
    float s = 0.f, s2 = 0.f;
#pragma unroll
    for (int i = 0; i < 8; ++i) { s += x[i]; s2 = fmaf(x[i], x[i], s2); }
    for (int off = 32; off; off >>= 1) {
        s += __shfl_xor(s, off);
        s2 += __shfl_xor(s2, off);
    }
    const float mean = s * (1.f / DMODEL);
    const float var = s2 * (1.f / DMODEL) - mean * mean;
    const float inv = rsqrtf(var + 1e-5f);
    float4 g0 = *(const float4*)(gamma + lane * 8);
    float4 g1 = *(const float4*)(gamma + lane * 8 + 4);
    float4 be0 = *(const float4*)(beta + lane * 8);
    float4 be1 = *(const float4*)(beta + lane * 8 + 4);
    float y[8];
    y[0] = (x[0] - mean) * inv * g0.x + be0.x;
    y[1] = (x[1] - mean) * inv * g0.y + be0.y;
    y[2] = (x[2] - mean) * inv * g0.z + be0.z;
    y[3] = (x[3] - mean) * inv * g0.w + be0.w;
    y[4] = (x[4] - mean) * inv * g1.x + be1.x;
    y[5] = (x[5] - mean) * inv * g1.y + be1.y;
    y[6] = (x[6] - mean) * inv * g1.z + be1.z;
    y[7] = (x[7] - mean) * inv * g1.w + be1.w;
    if (OUTF32) {
        float* o = (float*)O + (long long)(r / ogrp) * ostride + (long long)(r % ogrp) * DMODEL;
        *(float4*)(o + lane * 8) = *(float4*)&y[0];
        *(float4*)(o + lane * 8 + 4) = *(float4*)&y[4];
    } else {
        ushort_t* o = (ushort_t*)O + (long long)(r / ogrp) * ostride + (long long)(r % ogrp) * DMODEL;
        ushort_t ob[8];
#pragma unroll
        for (int i = 0; i < 8; ++i) ob[i] = f2b(y[i]);
        *(uint4*)(o + lane * 8) = *(const uint4*)ob;
    }
}

__global__ void lens_k(const int* __restrict__ ends, int* __restrict__ lens)
{
    int i = blockIdx.x * 256 + threadIdx.x;
    if (i >= NB * NT) return;
    int t = i & (NT - 1);
    int prev = t ? ends[i - 1] : 0;
    int l = ends[i] - prev;
    if (l > SEGL) l = SEGL;
    lens[i] = l;
}

// ---------------------------------------------------------------------------
extern "C" void kernel_launch(void* const* d_in, const int* in_sizes, int n_in,
                              void* d_out, int out_size, void* d_ws, size_t ws_size,
                              hipStream_t stream)
{
    const float* seqs = (const float*)d_in[0];
    const int*   ends = (const int*)d_in[1];
    const float* Wsrc[13] = {
        (const float*)d_in[2],                      // eWin
        (const float*)d_in[3], (const float*)d_in[4],   // eWq eWk
        (const float*)d_in[5], (const float*)d_in[6],   // eWv eWo
        (const float*)d_in[9], (const float*)d_in[10],  // eF1 eF2
        (const float*)d_in[13], (const float*)d_in[14], // cWq cWk
        (const float*)d_in[15], (const float*)d_in[16], // cWv cWo
        (const float*)d_in[19], (const float*)d_in[20], // cF1 cF2
    };
    const float* eG1 = (const float*)d_in[7],  *eB1 = (const float*)d_in[8];
    const float* eG2 = (const float*)d_in[11], *eB2 = (const float*)d_in[12];
    const float* cG1 = (const float*)d_in[17], *cB1 = (const float*)d_in[18];
    const float* cG2 = (const float*)d_in[21], *cB2 = (const float*)d_in[22];
    float* out = (float*)d_out;

    // ---- workspace (ushort bf16 elements) ----
    ushort_t* ws = (ushort_t*)d_ws;
    const long long SEQROW = (long long)NT * SEGL * DMODEL;    // 409600 elems (b-stride)
    ushort_t* SEQB = ws;                                       // 26,214,400
    ushort_t* WT   = SEQB + 26214400LL;                        // 6,553,600
    ushort_t* ENC  = WT   + 6553600LL;                         // 26,214,400
    ushort_t* BUF0 = ENC  + 26214400LL;                        // 6,553,600 each
    ushort_t* BUF1 = BUF0 + 6553600LL;
    ushort_t* BUF2 = BUF1 + 6553600LL;
    ushort_t* BUF3 = BUF2 + 6553600LL;
    ushort_t* BUF4 = BUF3 + 6553600LL;
    ushort_t* MID  = BUF4 + 6553600LL;                         // 26,214,400
    ushort_t* OUTB = MID  + 26214400LL;                        // 1,638,400
    int*      lens = (int*)(OUTB + 1638400LL);

    // transposed weight offsets (elements)
    const long long wtoff[13] = {
        0, 262144, 524288, 786432, 1048576,            // eWin,eWq,eWk,eWv,eWo
        1310720, 2359296,                               // eF1(2048x512), eF2(512x2048)
        3407872, 3670016, 3932160, 4194304,             // cWq,cWk,cWv,cWo
        4456448, 5505024                                 // cF1, cF2
    };
    const int wK[13] = {512,512,512,512,512, 512,2048, 512,512,512,512, 512,2048};
    const int wN[13] = {512,512,512,512,512, 2048,512, 512,512,512,512, 2048,512};

    // ---- prep: convert seqs, transpose weights, lens ----
    cvt_k<<<12800, 256, 0, stream>>>(seqs, SEQB, 26214400LL);
    for (int w = 0; w < 13; ++w) {
        dim3 g(wN[w] / 32, wK[w] / 32);
        wtrans_k<<<g, 256, 0, stream>>>(Wsrc[w], WT + wtoff[w], wK[w], wN[w]);
    }
    lens_k<<<4, 256, 0, stream>>>(ends, lens);

    const ushort_t* eWin = WT + wtoff[0];
    const ushort_t* eWq  = WT + wtoff[1], *eWk = WT + wtoff[2];
    const ushort_t* eWv  = WT + wtoff[3], *eWo = WT + wtoff[4];
    const ushort_t* eF1  = WT + wtoff[5], *eF2 = WT + wtoff[6];
    const ushort_t* cWq  = WT + wtoff[7], *cWk = WT + wtoff[8];
    const ushort_t* cWv  = WT + wtoff[9], *cWo = WT + wtoff[10];
    const ushort_t* cF1  = WT + wtoff[11], *cF2 = WT + wtoff[12];

    auto gemmL = [&](const ushort_t* A, int agrp, long long astr, const ushort_t* Bt,
                     ushort_t* C, int M, int N, int K, int relu) {
        dim3 g(N / 128, M / 128);
        mfma_gemm<128, 128, 2, 2><<<g, 256, 0, stream>>>(A, agrp, astr, Bt, C, M, N, K, relu);
    };
    auto gemmS = [&](const ushort_t* A, int agrp, long long astr, const ushort_t* Bt,
                     ushort_t* C, int M, int N, int K, int relu) {
        dim3 g(N / 128, M / 64);
        mfma_gemm<64, 128, 2, 2><<<g, 256, 0, stream>>>(A, agrp, astr, Bt, C, M, N, K, relu);
    };

    // ---------------- Phase 1: all encoders, chunks of G=4 segments ----------
    const int G = 4;
    const int Mc = NB * G * SEGL;   // 12800
    for (int c = 0; c < NT / G; ++c) {
        const int t0 = c * G;
        const ushort_t* Abase = SEQB + (long long)t0 * SEGL * DMODEL;
        ushort_t* ENCc = ENC + (long long)t0 * SEGL * DMODEL;
        gemmL(Abase, G * SEGL, SEQROW, eWin, BUF0, Mc, 512, 512, 0);
        gemmL(BUF0, Mc, 0, eWq, BUF1, Mc, 512, 512, 0);
        gemmL(BUF0, Mc, 0, eWk, BUF2, Mc, 512, 512, 0);
        gemmL(BUF0, Mc, 0, eWv, BUF3, Mc, 512, 512, 0);
        attn_k<<<NB * G * NHEAD, 256, 0, stream>>>(BUF1, BUF2, BUF3, BUF4, lens, G, t0);
        gemmL(BUF4, Mc, 0, eWo, BUF1, Mc, 512, 512, 0);
        add_ln_k<false><<<Mc / 4, 256, 0, stream>>>(BUF0, Mc, 0, BUF1, eG1, eB1, BUF2, Mc, 0, Mc);
        gemmL(BUF2, Mc, 0, eF1, MID, Mc, 2048, 512, 1);
        gemmL(MID, Mc, 0, eF2, BUF3, Mc, 512, 2048, 0);
        add_ln_k<false><<<Mc / 4, 256, 0, stream>>>(BUF2, Mc, 0, BUF3, eG2, eB2,
                                                    ENCc, G * SEGL, SEQROW, Mc);
    }

    // ---------------- Phase 2: 15 sequential connection steps ----------------
    const int Ms = NB * SEGL;   // 3200
    for (int t = 1; t < NT; ++t) {
        const ushort_t* currA = ENC + (long long)t * SEGL * DMODEL; // grouped (50, SEQROW)
        const ushort_t* prevA; int pg; long long ps;
        if (t == 1) { prevA = ENC;  pg = SEGL; ps = SEQROW; }
        else        { prevA = OUTB; pg = Ms;   ps = 0; }
        gemmS(currA, SEGL, SEQROW, cWq, BUF1, Ms, 512, 512, 0);
        gemmS(prevA, pg, ps,       cWk, BUF2, Ms, 512, 512, 0);
        gemmS(prevA, pg, ps,       cWv, BUF3, Ms, 512, 512, 0);
        attn_k<<<NB * NHEAD, 256, 0, stream>>>(BUF1, BUF2, BUF3, BUF4, nullptr, 1, 0);
        gemmS(BUF4, Ms, 0, cWo, BUF0, Ms, 512, 512, 0);
        add_ln_k<false><<<Ms / 4, 256, 0, stream>>>(currA, SEGL, SEQROW, BUF0, cG1, cB1,
                                                    BUF1, Ms, 0, Ms);
        gemmS(BUF1, Ms, 0, cF1, MID, Ms, 2048, 512, 1);
        gemmS(MID, Ms, 0, cF2, BUF0, Ms, 512, 2048, 0);
        if (t == NT - 1)
            add_ln_k<true><<<Ms / 4, 256, 0, stream>>>(BUF1, Ms, 0, BUF0, cG2, cB2,
                                                       out, Ms, 0, Ms);
        else
            add_ln_k<false><<<Ms / 4, 256, 0, stream>>>(BUF1, Ms, 0, BUF0, cG2, cB2,
                                                        OUTB, Ms, 0, Ms);
    }
}

// Round 3
// 3751.458 us; speedup vs baseline: 3.3021x; 1.3504x over previous
//
#include <hip/hip_runtime.h>

// RecurrentTransformerEncoder on MI355X — round 3: fix attn LDS bank
// conflicts (pad K/V rows to 68 floats, wave-uniform q row, fused softmax)
// + fused QKV / KV projection GEMMs.
// B=64, T=16, SEG=50, E=D=512, H=8, DH=64, F=2048.

#define NB   64
#define NT   16
#define SEGL 50
#define DMODEL 512
#define DFF  2048
#define NHEAD 8
#define DHEAD 64

typedef unsigned short ushort_t;
typedef __attribute__((ext_vector_type(8))) short bfrag;   // 8 bf16 (4 VGPRs)
typedef __attribute__((ext_vector_type(4))) float ffrag;   // 4 fp32 acc

__device__ __forceinline__ ushort_t f2b(float x) {
    union { float f; unsigned u; } c; c.f = x;
    unsigned r = c.u + 0x7fffu + ((c.u >> 16) & 1u);
    return (ushort_t)(r >> 16);
}

#define GLOAD_LDS16(g, l) __builtin_amdgcn_global_load_lds( \
    (const __attribute__((address_space(1))) void*)(g),      \
    (__attribute__((address_space(3))) void*)(l), 16, 0, 0)

// ---------------------------------------------------------------------------
// MFMA GEMM: C[M,N](bf16) = relu?(A[M,K](bf16) @ Bt[N,K](bf16)^T)
// A rows remapped: row m at A + (m/agrp)*astride + (m%agrp)*K.
// 256 threads = 4 waves (WROWS x WCOLS), mfma_f32_16x16x32_bf16, LDS staged
// in fragment order via global_load_lds width=16 (m97 pattern).
// ---------------------------------------------------------------------------
template<int BM, int BN, int WROWS, int WCOLS>
__global__ __launch_bounds__(256) void mfma_gemm(
    const ushort_t* __restrict__ A, int agrp, long long astride,
    const ushort_t* __restrict__ Bt, ushort_t* __restrict__ C,
    int M, int N, int K, int relu)
{
    constexpr int WM = BM / WROWS, WN = BN / WCOLS;
    constexpr int SM = WM / 16, SN = WN / 16;
    constexpr int NSUBA = BM / 16, NSUBB = BN / 16;
    constexpr int NSUB = NSUBA + NSUBB;
    constexpr int SPW = NSUB / 4;
    __shared__ ushort_t lds[NSUB * 512];

    const int tid = threadIdx.x;
    const int wave = tid >> 6, lane = tid & 63;
    const int wrow = wave / WCOLS, wcol = wave % WCOLS;
    const int bm = blockIdx.y * BM, bn = blockIdx.x * BN;
    const int lm = lane & 15, lq = lane >> 4;

    ffrag acc[SM][SN];
#pragma unroll
    for (int i = 0; i < SM; ++i)
#pragma unroll
        for (int j = 0; j < SN; ++j) acc[i][j] = (ffrag){0.f, 0.f, 0.f, 0.f};

    const ushort_t* gptr[SPW];
    ushort_t* lptr[SPW];
#pragma unroll
    for (int i = 0; i < SPW; ++i) {
        int s = wave * SPW + i;
        if (s < NSUBA) {
            int m = bm + s * 16 + lm;
            gptr[i] = A + (long long)(m / agrp) * astride
                        + (long long)(m % agrp) * K + lq * 8;
        } else {
            int n = bn + (s - NSUBA) * 16 + lm;
            gptr[i] = Bt + (long long)n * K + lq * 8;
        }
        lptr[i] = &lds[s * 512];
    }

    for (int kk = 0; kk < K; kk += 32) {
        __syncthreads();
#pragma unroll
        for (int i = 0; i < SPW; ++i)
            GLOAD_LDS16(gptr[i] + kk, lptr[i]);
        __builtin_amdgcn_s_waitcnt(0);
        __syncthreads();

        bfrag af[SM], bfg[SN];
#pragma unroll
        for (int i = 0; i < SM; ++i)
            af[i] = *(const bfrag*)&lds[(wrow * SM + i) * 512 + lane * 8];
#pragma unroll
        for (int j = 0; j < SN; ++j)
            bfg[j] = *(const bfrag*)&lds[(NSUBA + wcol * SN + j) * 512 + lane * 8];
#pragma unroll
        for (int i = 0; i < SM; ++i)
#pragma unroll
            for (int j = 0; j < SN; ++j)
                acc[i][j] = __builtin_amdgcn_mfma_f32_16x16x32_bf16(
                    af[i], bfg[j], acc[i][j], 0, 0, 0);
    }

    // D[row=(lane>>4)*4+reg][col=lane&15]  (m89/m91-verified)
#pragma unroll
    for (int i = 0; i < SM; ++i)
#pragma unroll
        for (int j = 0; j < SN; ++j) {
            int col = bn + wcol * WN + j * 16 + lm;
#pragma unroll
            for (int r = 0; r < 4; ++r) {
                int row = bm + wrow * WM + i * 16 + lq * 4 + r;
                float v = acc[i][j][r];
                if (relu) v = fmaxf(v, 0.f);
                C[(long long)row * N + col] = f2b(v);
            }
        }
}

// ---------------------------------------------------------------------------
// Weight transpose+convert: W[K][N] fp32 -> Wt[N][K] bf16.
// ---------------------------------------------------------------------------
__global__ __launch_bounds__(256) void wtrans_k(
    const float* __restrict__ W, ushort_t* __restrict__ Wt, int K, int N)
{
    __shared__ float t[32][33];
    const int bk = blockIdx.y * 32, bn = blockIdx.x * 32;
    const int tx = threadIdx.x & 31, ty = threadIdx.x >> 5;
    for (int i = ty; i < 32; i += 8)
        t[i][tx] = W[(long long)(bk + i) * N + bn + tx];
    __syncthreads();
    for (int i = ty; i < 32; i += 8)
        Wt[(long long)(bn + i) * K + bk + tx] = f2b(t[tx][i]);
}

__global__ __launch_bounds__(256) void cvt_k(
    const float* __restrict__ in, ushort_t* __restrict__ out, long long n)
{
    long long i = ((long long)blockIdx.x * 256 + threadIdx.x) * 8;
    if (i >= n) return;
    float4 a = *(const float4*)(in + i);
    float4 b = *(const float4*)(in + i + 4);
    ushort_t o[8] = {f2b(a.x), f2b(a.y), f2b(a.z), f2b(a.w),
                     f2b(b.x), f2b(b.y), f2b(b.z), f2b(b.w)};
    *(uint4*)(out + i) = *(const uint4*)o;
}

// ---------------------------------------------------------------------------
// Attention for one (sequence, head). Q/K/V bf16 with row strides qrs / kvrs
// (head h at cols h*64); O packed stride 512. fp32 compute in LDS.
// K/V LDS rows padded to 68 floats: bank = 4*lane + d -> 8 consecutive lanes
// cover all 32 banks (2-way across wave = free). Scores: query row is
// wave-uniform (q reads broadcast), lane j owns key j; softmax fused in
// registers via shuffles; only P goes back to LDS.
// ---------------------------------------------------------------------------
__global__ __launch_bounds__(256) void attn_k(
    const ushort_t* __restrict__ Q, long long qrs,
    const ushort_t* __restrict__ K, const ushort_t* __restrict__ V, long long kvrs,
    ushort_t* __restrict__ O,
    const int* __restrict__ lens, int G, int t0)
{
    __shared__ float qs[SEGL][DHEAD];        // broadcast reads, no pad needed
    __shared__ float ks[SEGL][DHEAD + 4];
    __shared__ float vs[SEGL][DHEAD + 4];
    __shared__ float ps[SEGL][SEGL];
    const int n = blockIdx.x >> 3;
    const int h = blockIdx.x & 7;
    const int tid = threadIdx.x;
    int len = SEGL;
    if (lens) {
        int b = n / G, t = t0 + (n % G);
        len = lens[b * NT + t];
        if (len > SEGL) len = SEGL;
    }
    // load + bf16->fp32: 400 items of 8 elems each per matrix
    for (int idx = tid; idx < SEGL * 8; idx += 256) {
        int s = idx >> 3, d8 = (idx & 7) << 3;
        long long qoff = (long long)(n * SEGL + s) * qrs + h * DHEAD + d8;
        long long koff = (long long)(n * SEGL + s) * kvrs + h * DHEAD + d8;
        uint4 q4 = *(const uint4*)(Q + qoff);
        uint4 k4 = *(const uint4*)(K + koff);
        uint4 v4 = *(const uint4*)(V + koff);
        const unsigned* qa = (const unsigned*)&q4;
        const unsigned* ka = (const unsigned*)&k4;
        const unsigned* va = (const unsigned*)&v4;
#pragma unroll
        for (int c = 0; c < 4; ++c) {
            union { unsigned u; float f; } lo, hi;
            lo.u = qa[c] << 16; hi.u = qa[c] & 0xffff0000u;
            qs[s][d8 + 2 * c] = lo.f; qs[s][d8 + 2 * c + 1] = hi.f;
            lo.u = ka[c] << 16; hi.u = ka[c] & 0xffff0000u;
            ks[s][d8 + 2 * c] = lo.f; ks[s][d8 + 2 * c + 1] = hi.f;
            lo.u = va[c] << 16; hi.u = va[c] & 0xffff0000u;
            vs[s][d8 + 2 * c] = lo.f; vs[s][d8 + 2 * c + 1] = hi.f;
        }
    }
    __syncthreads();
    const int wave = tid >> 6, lane = tid & 63;
    const float* krow = &ks[(lane < SEGL) ? lane : 0][0];
    for (int r = wave; r < SEGL; r += 4) {
        float dot = 0.f;
#pragma unroll
        for (int d = 0; d < DHEAD; d += 4) {
            float4 qv = *(const float4*)&qs[r][d];   // wave-uniform: broadcast
            float4 kv = *(const float4*)(krow + d);  // padded: conflict-free
            dot = fmaf(qv.x, kv.x, dot);
            dot = fmaf(qv.y, kv.y, dot);
            dot = fmaf(qv.z, kv.z, dot);
            dot = fmaf(qv.w, kv.w, dot);
        }
        float x = (lane < SEGL) ? ((lane < len) ? dot * 0.125f : -1e9f) : -1e30f;
        float m = x;
        for (int off = 32; off; off >>= 1) m = fmaxf(m, __shfl_xor(m, off));
        float e = (lane < SEGL) ? __expf(x - m) : 0.f;
        float ssum = e;
        for (int off = 32; off; off >>= 1) ssum += __shfl_xor(ssum, off);
        if (lane < SEGL) ps[r][lane] = e / ssum;
    }
    __syncthreads();
    // O = P @ V : ps[s][j] broadcast (s wave-uniform), vs[j][d] stride-1
    for (int idx = tid; idx < SEGL * DHEAD; idx += 256) {
        int s = idx >> 6, d = idx & 63;
        float a = 0.f;
#pragma unroll 10
        for (int j = 0; j < SEGL; ++j) a = fmaf(ps[s][j], vs[j][d], a);
        O[(long long)(n * SEGL + s) * DMODEL + h * DHEAD + d] = f2b(a);
    }
}

// ---------------------------------------------------------------------------
// out = LN(a + b)*gamma + beta, rows of 512, bf16 in, bf16/fp32 out.
// ---------------------------------------------------------------------------
template<bool OUTF32>
__global__ __launch_bounds__(256) void add_ln_k(
    const ushort_t* __restrict__ A, int agrp, long long astride,
    const ushort_t* __restrict__ Bv,
    const float* __restrict__ gamma, const float* __restrict__ beta,
    void* __restrict__ O, int ogrp, long long ostride, int M)
{
    const int wave = threadIdx.x >> 6, lane = threadIdx.x & 63;
    const int r = blockIdx.x * 4 + wave;
    if (r >= M) return;
    const ushort_t* a = A + (long long)(r / agrp) * astride + (long long)(r % agrp) * DMODEL;
    const ushort_t* b = Bv + (long long)r * DMODEL;
    float x[8];
    {
        uint4 a4 = *(const uint4*)(a + lane * 8);
        uint4 b4 = *(const uint4*)(b + lane * 8);
        const unsigned* aa = (const unsigned*)&a4;
        const unsigned* bb = (const unsigned*)&b4;
#pragma unroll
        for (int c = 0; c < 4; ++c) {
            union { unsigned u; float f; } alo, ahi, blo, bhi;
            alo.u = aa[c] << 16; ahi.u = aa[c] & 0xffff0000u;
            blo.u = bb[c] << 16; bhi.u = bb[c] & 0xffff0000u;
            x[2 * c]     = alo.f + blo.f;
            x[2 * c + 1] = ahi.f + bhi.f;
        }
    }
    float s = 0.f, s2 = 0.f;
#pragma unroll
    for (int i = 0; i < 8; ++i) { s += x[i]; s2 = fmaf(x[i], x[i], s2); }
    for (int off = 32; off; off >>= 1) {
        s += __shfl_xor(s, off);
        s2 += __shfl_xor(s2, off);
    }
    const float mean = s * (1.f / DMODEL);
    const float var = s2 * (1.f / DMODEL) - mean * mean;
    const float inv = rsqrtf(var + 1e-5f);
    float4 g0 = *(const float4*)(gamma + lane * 8);
    float4 g1 = *(const float4*)(gamma + lane * 8 + 4);
    float4 be0 = *(const float4*)(beta + lane * 8);
    float4 be1 = *(const float4*)(beta + lane * 8 + 4);
    float y[8];
    y[0] = (x[0] - mean) * inv * g0.x + be0.x;
    y[1] = (x[1] - mean) * inv * g0.y + be0.y;
    y[2] = (x[2] - mean) * inv * g0.z + be0.z;
    y[3] = (x[3] - mean) * inv * g0.w + be0.w;
    y[4] = (x[4] - mean) * inv * g1.x + be1.x;
    y[5] = (x[5] - mean) * inv * g1.y + be1.y;
    y[6] = (x[6] - mean) * inv * g1.z + be1.z;
    y[7] = (x[7] - mean) * inv * g1.w + be1.w;
    if (OUTF32) {
        float* o = (float*)O + (long long)(r / ogrp) * ostride + (long long)(r % ogrp) * DMODEL;
        *(float4*)(o + lane * 8) = *(float4*)&y[0];
        *(float4*)(o + lane * 8 + 4) = *(float4*)&y[4];
    } else {
        ushort_t* o = (ushort_t*)O + (long long)(r / ogrp) * ostride + (long long)(r % ogrp) * DMODEL;
        ushort_t ob[8];
#pragma unroll
        for (int i = 0; i < 8; ++i) ob[i] = f2b(y[i]);
        *(uint4*)(o + lane * 8) = *(const uint4*)ob;
    }
}

__global__ void lens_k(const int* __restrict__ ends, int* __restrict__ lens)
{
    int i = blockIdx.x * 256 + threadIdx.x;
    if (i >= NB * NT) return;
    int t = i & (NT - 1);
    int prev = t ? ends[i - 1] : 0;
    int l = ends[i] - prev;
    if (l > SEGL) l = SEGL;
    lens[i] = l;
}

// ---------------------------------------------------------------------------
extern "C" void kernel_launch(void* const* d_in, const int* in_sizes, int n_in,
                              void* d_out, int out_size, void* d_ws, size_t ws_size,
                              hipStream_t stream)
{
    const float* seqs = (const float*)d_in[0];
    const int*   ends = (const int*)d_in[1];
    const float* eG1 = (const float*)d_in[7],  *eB1 = (const float*)d_in[8];
    const float* eG2 = (const float*)d_in[11], *eB2 = (const float*)d_in[12];
    const float* cG1 = (const float*)d_in[17], *cB1 = (const float*)d_in[18];
    const float* cG2 = (const float*)d_in[21], *cB2 = (const float*)d_in[22];
    float* out = (float*)d_out;

    // ---- workspace (ushort bf16 elements) ----
    ushort_t* ws = (ushort_t*)d_ws;
    const long long SEQROW = (long long)NT * SEGL * DMODEL;    // 409600 (b-stride)
    ushort_t* SEQB = ws;                                       // 26,214,400
    ushort_t* WT   = SEQB + 26214400LL;                        // 6,553,600
    ushort_t* ENC  = WT   + 6553600LL;                         // 26,214,400
    ushort_t* BUF0 = ENC  + 26214400LL;                        // 6,553,600
    ushort_t* QKV  = BUF0 + 6553600LL;                         // 19,660,800 (12800x1536)
    ushort_t* BUF4 = QKV  + 19660800LL;                        // 6,553,600
    ushort_t* BUF1 = BUF4 + 6553600LL;                         // 6,553,600
    ushort_t* BUF2 = BUF1 + 6553600LL;                         // 6,553,600
    ushort_t* MID  = BUF2 + 6553600LL;                         // 26,214,400
    ushort_t* OUTB = MID  + 26214400LL;                        // 1,638,400
    int*      lens = (int*)(OUTB + 1638400LL);

    // transposed-weight element offsets inside WT
    // eWinT=0 | WQKVe (eWq,eWk,eWv) | eWoT | eF1T | eF2T | cWqT | cKV (cWk,cWv) | cWoT | cF1T | cF2T
    const ushort_t* eWinT = WT + 0;
    const ushort_t* WQKVe = WT + 262144;      // 1536 x 512
    const ushort_t* eWoT  = WT + 1048576;
    const ushort_t* eF1T  = WT + 1310720;     // 2048 x 512
    const ushort_t* eF2T  = WT + 2359296;     // 512 x 2048
    const ushort_t* cWqT  = WT + 3407872;
    const ushort_t* cKV   = WT + 3670016;     // 1024 x 512
    const ushort_t* cWoT  = WT + 4194304;
    const ushort_t* cF1T  = WT + 4456448;
    const ushort_t* cF2T  = WT + 5505024;

    struct WMap { int src; long long dst; int K, N; };
    const WMap wm[13] = {
        {2,  0,       512, 512},   // eWin
        {3,  262144,  512, 512},   // eWq  -> WQKVe rows 0-511
        {4,  524288,  512, 512},   // eWk  -> rows 512-1023
        {5,  786432,  512, 512},   // eWv  -> rows 1024-1535
        {6,  1048576, 512, 512},   // eWo
        {9,  1310720, 512, 2048},  // eF1
        {10, 2359296, 2048, 512},  // eF2
        {13, 3407872, 512, 512},   // cWq
        {14, 3670016, 512, 512},   // cWk -> cKV rows 0-511
        {15, 3932160, 512, 512},   // cWv -> rows 512-1023
        {16, 4194304, 512, 512},   // cWo
        {19, 4456448, 512, 2048},  // cF1
        {20, 5505024, 2048, 512},  // cF2
    };

    cvt_k<<<12800, 256, 0, stream>>>(seqs, SEQB, 26214400LL);
    for (int w = 0; w < 13; ++w) {
        dim3 g(wm[w].N / 32, wm[w].K / 32);
        wtrans_k<<<g, 256, 0, stream>>>((const float*)d_in[wm[w].src],
                                        WT + wm[w].dst, wm[w].K, wm[w].N);
    }
    lens_k<<<4, 256, 0, stream>>>(ends, lens);

    auto gemmL = [&](const ushort_t* A, int agrp, long long astr, const ushort_t* Bt,
                     ushort_t* C, int M, int N, int K, int relu) {
        dim3 g(N / 128, M / 128);
        mfma_gemm<128, 128, 2, 2><<<g, 256, 0, stream>>>(A, agrp, astr, Bt, C, M, N, K, relu);
    };
    auto gemmS = [&](const ushort_t* A, int agrp, long long astr, const ushort_t* Bt,
                     ushort_t* C, int M, int N, int K, int relu) {
        dim3 g(N / 128, M / 64);
        mfma_gemm<64, 128, 2, 2><<<g, 256, 0, stream>>>(A, agrp, astr, Bt, C, M, N, K, relu);
    };

    // ---------------- Phase 1: all encoders, chunks of G=4 segments ----------
    const int G = 4;
    const int Mc = NB * G * SEGL;   // 12800
    for (int c = 0; c < NT / G; ++c) {
        const int t0 = c * G;
        const ushort_t* Abase = SEQB + (long long)t0 * SEGL * DMODEL;
        ushort_t* ENCc = ENC + (long long)t0 * SEGL * DMODEL;
        gemmL(Abase, G * SEGL, SEQROW, eWinT, BUF0, Mc, 512, 512, 0);
        gemmL(BUF0, Mc, 0, WQKVe, QKV, Mc, 1536, 512, 0);        // fused QKV
        attn_k<<<NB * G * NHEAD, 256, 0, stream>>>(
            QKV, 1536, QKV + 512, QKV + 1024, 1536, BUF4, lens, G, t0);
        gemmL(BUF4, Mc, 0, eWoT, BUF1, Mc, 512, 512, 0);
        add_ln_k<false><<<Mc / 4, 256, 0, stream>>>(BUF0, Mc, 0, BUF1, eG1, eB1,
                                                    BUF2, Mc, 0, Mc);
        gemmL(BUF2, Mc, 0, eF1T, MID, Mc, 2048, 512, 1);
        gemmL(MID, Mc, 0, eF2T, BUF1, Mc, 512, 2048, 0);
        add_ln_k<false><<<Mc / 4, 256, 0, stream>>>(BUF2, Mc, 0, BUF1, eG2, eB2,
                                                    ENCc, G * SEGL, SEQROW, Mc);
    }

    // ---------------- Phase 2: 15 sequential connection steps ----------------
    const int Ms = NB * SEGL;   // 3200
    for (int t = 1; t < NT; ++t) {
        const ushort_t* currA = ENC + (long long)t * SEGL * DMODEL; // grouped (50, SEQROW)
        const ushort_t* prevA; int pg; long long ps;
        if (t == 1) { prevA = ENC;  pg = SEGL; ps = SEQROW; }
        else        { prevA = OUTB; pg = Ms;   ps = 0; }
        gemmS(currA, SEGL, SEQROW, cWqT, BUF1, Ms, 512, 512, 0);
        gemmS(prevA, pg, ps, cKV, QKV, Ms, 1024, 512, 0);        // fused KV
        attn_k<<<NB * NHEAD, 256, 0, stream>>>(
            BUF1, 512, QKV, QKV + 512, 1024, BUF4, nullptr, 1, 0);
        gemmS(BUF4, Ms, 0, cWoT, BUF0, Ms, 512, 512, 0);
        add_ln_k<false><<<Ms / 4, 256, 0, stream>>>(currA, SEGL, SEQROW, BUF0, cG1, cB1,
                                                    BUF2, Ms, 0, Ms);
        gemmS(BUF2, Ms, 0, cF1T, MID, Ms, 2048, 512, 1);
        gemmS(MID, Ms, 0, cF2T, BUF0, Ms, 512, 2048, 0);
        if (t == NT - 1)
            add_ln_k<true><<<Ms / 4, 256, 0, stream>>>(BUF2, Ms, 0, BUF0, cG2, cB2,
                                                       out, Ms, 0, Ms);
        else
            add_ln_k<false><<<Ms / 4, 256, 0, stream>>>(BUF2, Ms, 0, BUF0, cG2, cB2,
                                                        OUTB, Ms, 0, Ms);
    }
}

// Round 4
// 3154.009 us; speedup vs baseline: 3.9276x; 1.1894x over previous
//
#include <hip/hip_runtime.h>

// RecurrentTransformerEncoder on MI355X — round 4: MFMA attention +
// phase-2 Q-projection hoisted into one batched GEMM.
// B=64, T=16, SEG=50, E=D=512, H=8, DH=64, F=2048.

#define NB   64
#define NT   16
#define SEGL 50
#define DMODEL 512
#define DFF  2048
#define NHEAD 8
#define DHEAD 64

typedef unsigned short ushort_t;
typedef __attribute__((ext_vector_type(8))) short bfrag;   // 8 bf16 (4 VGPRs)
typedef __attribute__((ext_vector_type(4))) float ffrag;   // 4 fp32 acc

__device__ __forceinline__ ushort_t f2b(float x) {
    union { float f; unsigned u; } c; c.f = x;
    unsigned r = c.u + 0x7fffu + ((c.u >> 16) & 1u);
    return (ushort_t)(r >> 16);
}

#define GLOAD_LDS16(g, l) __builtin_amdgcn_global_load_lds( \
    (const __attribute__((address_space(1))) void*)(g),      \
    (__attribute__((address_space(3))) void*)(l), 16, 0, 0)

// ---------------------------------------------------------------------------
// MFMA GEMM: C[M,N](bf16) = relu?(A[M,K](bf16) @ Bt[N,K](bf16)^T)
// A rows remapped: row m at A + (m/agrp)*astride + (m%agrp)*K.
// ---------------------------------------------------------------------------
template<int BM, int BN, int WROWS, int WCOLS>
__global__ __launch_bounds__(256) void mfma_gemm(
    const ushort_t* __restrict__ A, int agrp, long long astride,
    const ushort_t* __restrict__ Bt, ushort_t* __restrict__ C,
    int M, int N, int K, int relu)
{
    constexpr int WM = BM / WROWS, WN = BN / WCOLS;
    constexpr int SM = WM / 16, SN = WN / 16;
    constexpr int NSUBA = BM / 16, NSUBB = BN / 16;
    constexpr int NSUB = NSUBA + NSUBB;
    constexpr int SPW = NSUB / 4;
    __shared__ ushort_t lds[NSUB * 512];

    const int tid = threadIdx.x;
    const int wave = tid >> 6, lane = tid & 63;
    const int wrow = wave / WCOLS, wcol = wave % WCOLS;
    const int bm = blockIdx.y * BM, bn = blockIdx.x * BN;
    const int lm = lane & 15, lq = lane >> 4;

    ffrag acc[SM][SN];
#pragma unroll
    for (int i = 0; i < SM; ++i)
#pragma unroll
        for (int j = 0; j < SN; ++j) acc[i][j] = (ffrag){0.f, 0.f, 0.f, 0.f};

    const ushort_t* gptr[SPW];
    ushort_t* lptr[SPW];
#pragma unroll
    for (int i = 0; i < SPW; ++i) {
        int s = wave * SPW + i;
        if (s < NSUBA) {
            int m = bm + s * 16 + lm;
            gptr[i] = A + (long long)(m / agrp) * astride
                        + (long long)(m % agrp) * K + lq * 8;
        } else {
            int n = bn + (s - NSUBA) * 16 + lm;
            gptr[i] = Bt + (long long)n * K + lq * 8;
        }
        lptr[i] = &lds[s * 512];
    }

    for (int kk = 0; kk < K; kk += 32) {
        __syncthreads();
#pragma unroll
        for (int i = 0; i < SPW; ++i)
            GLOAD_LDS16(gptr[i] + kk, lptr[i]);
        __builtin_amdgcn_s_waitcnt(0);
        __syncthreads();

        bfrag af[SM], bfg[SN];
#pragma unroll
        for (int i = 0; i < SM; ++i)
            af[i] = *(const bfrag*)&lds[(wrow * SM + i) * 512 + lane * 8];
#pragma unroll
        for (int j = 0; j < SN; ++j)
            bfg[j] = *(const bfrag*)&lds[(NSUBA + wcol * SN + j) * 512 + lane * 8];
#pragma unroll
        for (int i = 0; i < SM; ++i)
#pragma unroll
            for (int j = 0; j < SN; ++j)
                acc[i][j] = __builtin_amdgcn_mfma_f32_16x16x32_bf16(
                    af[i], bfg[j], acc[i][j], 0, 0, 0);
    }

    // D[row=(lane>>4)*4+reg][col=lane&15]
#pragma unroll
    for (int i = 0; i < SM; ++i)
#pragma unroll
        for (int j = 0; j < SN; ++j) {
            int col = bn + wcol * WN + j * 16 + lm;
#pragma unroll
            for (int r = 0; r < 4; ++r) {
                int row = bm + wrow * WM + i * 16 + lq * 4 + r;
                float v = acc[i][j][r];
                if (relu) v = fmaxf(v, 0.f);
                C[(long long)row * N + col] = f2b(v);
            }
        }
}

// ---------------------------------------------------------------------------
// Weight transpose+convert: W[K][N] fp32 -> Wt[N][K] bf16.
// ---------------------------------------------------------------------------
__global__ __launch_bounds__(256) void wtrans_k(
    const float* __restrict__ W, ushort_t* __restrict__ Wt, int K, int N)
{
    __shared__ float t[32][33];
    const int bk = blockIdx.y * 32, bn = blockIdx.x * 32;
    const int tx = threadIdx.x & 31, ty = threadIdx.x >> 5;
    for (int i = ty; i < 32; i += 8)
        t[i][tx] = W[(long long)(bk + i) * N + bn + tx];
    __syncthreads();
    for (int i = ty; i < 32; i += 8)
        Wt[(long long)(bn + i) * K + bk + tx] = f2b(t[tx][i]);
}

__global__ __launch_bounds__(256) void cvt_k(
    const float* __restrict__ in, ushort_t* __restrict__ out, long long n)
{
    long long i = ((long long)blockIdx.x * 256 + threadIdx.x) * 8;
    if (i >= n) return;
    float4 a = *(const float4*)(in + i);
    float4 b = *(const float4*)(in + i + 4);
    ushort_t o[8] = {f2b(a.x), f2b(a.y), f2b(a.z), f2b(a.w),
                     f2b(b.x), f2b(b.y), f2b(b.z), f2b(b.w)};
    *(uint4*)(out + i) = *(const uint4*)o;
}

// ---------------------------------------------------------------------------
// MFMA attention, one (sequence n, head h) per block. S=50->64 pad, D=64.
// Q rows at Q + n*qns + s*qrs + h*64 (bf16); K/V same with kns/kvrs.
// O packed rows of 512. QK^T and PV via mfma_f32_16x16x32_bf16; softmax
// fp32 in registers (C-layout rows spread over 16-lane groups).
// LDS arrays [64][72] bf16: 144B row stride = 16B-aligned, ~2-way banks.
// qs is reused to hold P (wave w only touches its own 16 rows).
// ---------------------------------------------------------------------------
__global__ __launch_bounds__(256) void attn_mfma_k(
    const ushort_t* __restrict__ Q, long long qns, long long qrs,
    const ushort_t* __restrict__ K, const ushort_t* __restrict__ V,
    long long kns, long long kvrs,
    ushort_t* __restrict__ O,
    const int* __restrict__ lens, int G, int t0)
{
    __shared__ ushort_t qs[64][72];   // Q, then P
    __shared__ ushort_t ks[64][72];
    __shared__ ushort_t vt[64][72];   // V^T: vt[d][j]
    const int n = blockIdx.x >> 3, h = blockIdx.x & 7;
    const int tid = threadIdx.x;
    const int wave = tid >> 6, lane = tid & 63;
    const int lm = lane & 15, lq = lane >> 4;
    int len = SEGL;
    if (lens) {
        int b = n / G, t = t0 + (n % G);
        len = lens[b * NT + t];
        if (len > SEGL) len = SEGL;
    }
    // zero vt (pad cols j>=50 must be 0: P=0 there but 0*NaN-stale = NaN)
    {
        uint4 z = {0, 0, 0, 0};
        uint4* vz = (uint4*)&vt[0][0];
        for (int i = tid; i < 64 * 72 / 8; i += 256) vz[i] = z;
    }
    __syncthreads();
    // stage Q,K rows + V transposed
    for (int idx = tid; idx < SEGL * 8; idx += 256) {
        int s = idx >> 3, d8 = (idx & 7) << 3;
        const ushort_t* qp = Q + (long long)n * qns + (long long)s * qrs + h * DHEAD + d8;
        const ushort_t* kp = K + (long long)n * kns + (long long)s * kvrs + h * DHEAD + d8;
        const ushort_t* vp = V + (long long)n * kns + (long long)s * kvrs + h * DHEAD + d8;
        *(uint4*)&qs[s][d8] = *(const uint4*)qp;
        *(uint4*)&ks[s][d8] = *(const uint4*)kp;
        uint4 v4 = *(const uint4*)vp;
        const ushort_t* vv = (const ushort_t*)&v4;
#pragma unroll
        for (int u = 0; u < 8; ++u) vt[d8 + u][s] = vv[u];
    }
    __syncthreads();

    // QK^T: wave w owns query m-tile w (rows w*16..+15)
    ffrag sc[4];
#pragma unroll
    for (int nt = 0; nt < 4; ++nt) sc[nt] = (ffrag){0.f, 0.f, 0.f, 0.f};
#pragma unroll
    for (int kt = 0; kt < 2; ++kt) {
        bfrag a = *(const bfrag*)&qs[wave * 16 + lm][kt * 32 + lq * 8];
#pragma unroll
        for (int nt = 0; nt < 4; ++nt) {
            bfrag b = *(const bfrag*)&ks[nt * 16 + lm][kt * 32 + lq * 8];
            sc[nt] = __builtin_amdgcn_mfma_f32_16x16x32_bf16(a, b, sc[nt], 0, 0, 0);
        }
    }
    __syncthreads();   // all qs a-frag reads done before P overwrites qs

    // softmax: row i = wave*16 + lq*4 + r lives in 16-lane group (lm spread)
#pragma unroll
    for (int r = 0; r < 4; ++r) {
        float x[4];
        float mx = -1e30f;
#pragma unroll
        for (int nt = 0; nt < 4; ++nt) {
            int col = nt * 16 + lm;
            x[nt] = (col < len) ? sc[nt][r] * 0.125f : -1e9f;
            mx = fmaxf(mx, x[nt]);
        }
        for (int off = 8; off; off >>= 1) mx = fmaxf(mx, __shfl_xor(mx, off));
        float e[4], se = 0.f;
#pragma unroll
        for (int nt = 0; nt < 4; ++nt) { e[nt] = __expf(x[nt] - mx); se += e[nt]; }
        for (int off = 8; off; off >>= 1) se += __shfl_xor(se, off);
        float inv = 1.f / se;
        int row = wave * 16 + lq * 4 + r;
#pragma unroll
        for (int nt = 0; nt < 4; ++nt)
            qs[row][nt * 16 + lm] = f2b(e[nt] * inv);
    }
    __syncthreads();

    // PV: O[i][d] = sum_j P[i][j] V[j][d]; A=P rows, B=vt rows (V^T)
    ffrag oc[4];
#pragma unroll
    for (int dt = 0; dt < 4; ++dt) oc[dt] = (ffrag){0.f, 0.f, 0.f, 0.f};
#pragma unroll
    for (int kt = 0; kt < 2; ++kt) {
        bfrag a = *(const bfrag*)&qs[wave * 16 + lm][kt * 32 + lq * 8];
#pragma unroll
        for (int dt = 0; dt < 4; ++dt) {
            bfrag b = *(const bfrag*)&vt[dt * 16 + lm][kt * 32 + lq * 8];
            oc[dt] = __builtin_amdgcn_mfma_f32_16x16x32_bf16(a, b, oc[dt], 0, 0, 0);
        }
    }
#pragma unroll
    for (int r = 0; r < 4; ++r) {
        int i = wave * 16 + lq * 4 + r;
        if (i < SEGL) {
            ushort_t* op = O + (long long)(n * SEGL + i) * DMODEL + h * DHEAD + lm;
#pragma unroll
            for (int dt = 0; dt < 4; ++dt)
                op[dt * 16] = f2b(oc[dt][r]);
        }
    }
}

// ---------------------------------------------------------------------------
// out = LN(a + b)*gamma + beta, rows of 512, bf16 in, bf16/fp32 out.
// ---------------------------------------------------------------------------
template<bool OUTF32>
__global__ __launch_bounds__(256) void add_ln_k(
    const ushort_t* __restrict__ A, int agrp, long long astride,
    const ushort_t* __restrict__ Bv,
    const float* __restrict__ gamma, const float* __restrict__ beta,
    void* __restrict__ O, int ogrp, long long ostride, int M)
{
    const int wave = threadIdx.x >> 6, lane = threadIdx.x & 63;
    const int r = blockIdx.x * 4 + wave;
    if (r >= M) return;
    const ushort_t* a = A + (long long)(r / agrp) * astride + (long long)(r % agrp) * DMODEL;
    const ushort_t* b = Bv + (long long)r * DMODEL;
    float x[8];
    {
        uint4 a4 = *(const uint4*)(a + lane * 8);
        uint4 b4 = *(const uint4*)(b + lane * 8);
        const unsigned* aa = (const unsigned*)&a4;
        const unsigned* bb = (const unsigned*)&b4;
#pragma unroll
        for (int c = 0; c < 4; ++c) {
            union { unsigned u; float f; } alo, ahi, blo, bhi;
            alo.u = aa[c] << 16; ahi.u = aa[c] & 0xffff0000u;
            blo.u = bb[c] << 16; bhi.u = bb[c] & 0xffff0000u;
            x[2 * c]     = alo.f + blo.f;
            x[2 * c + 1] = ahi.f + bhi.f;
        }
    }
    float s = 0.f, s2 = 0.f;
#pragma unroll
    for (int i = 0; i < 8; ++i) { s += x[i]; s2 = fmaf(x[i], x[i], s2); }
    for (int off = 32; off; off >>= 1) {
        s += __shfl_xor(s, off);
        s2 += __shfl_xor(s2, off);
    }
    const float mean = s * (1.f / DMODEL);
    const float var = s2 * (1.f / DMODEL) - mean * mean;
    const float inv = rsqrtf(var + 1e-5f);
    float4 g0 = *(const float4*)(gamma + lane * 8);
    float4 g1 = *(const float4*)(gamma + lane * 8 + 4);
    float4 be0 = *(const float4*)(beta + lane * 8);
    float4 be1 = *(const float4*)(beta + lane * 8 + 4);
    float y[8];
    y[0] = (x[0] - mean) * inv * g0.x + be0.x;
    y[1] = (x[1] - mean) * inv * g0.y + be0.y;
    y[2] = (x[2] - mean) * inv * g0.z + be0.z;
    y[3] = (x[3] - mean) * inv * g0.w + be0.w;
    y[4] = (x[4] - mean) * inv * g1.x + be1.x;
    y[5] = (x[5] - mean) * inv * g1.y + be1.y;
    y[6] = (x[6] - mean) * inv * g1.z + be1.z;
    y[7] = (x[7] - mean) * inv * g1.w + be1.w;
    if (OUTF32) {
        float* o = (float*)O + (long long)(r / ogrp) * ostride + (long long)(r % ogrp) * DMODEL;
        *(float4*)(o + lane * 8) = *(float4*)&y[0];
        *(float4*)(o + lane * 8 + 4) = *(float4*)&y[4];
    } else {
        ushort_t* o = (ushort_t*)O + (long long)(r / ogrp) * ostride + (long long)(r % ogrp) * DMODEL;
        ushort_t ob[8];
#pragma unroll
        for (int i = 0; i < 8; ++i) ob[i] = f2b(y[i]);
        *(uint4*)(o + lane * 8) = *(const uint4*)ob;
    }
}

__global__ void lens_k(const int* __restrict__ ends, int* __restrict__ lens)
{
    int i = blockIdx.x * 256 + threadIdx.x;
    if (i >= NB * NT) return;
    int t = i & (NT - 1);
    int prev = t ? ends[i - 1] : 0;
    int l = ends[i] - prev;
    if (l > SEGL) l = SEGL;
    lens[i] = l;
}

// ---------------------------------------------------------------------------
extern "C" void kernel_launch(void* const* d_in, const int* in_sizes, int n_in,
                              void* d_out, int out_size, void* d_ws, size_t ws_size,
                              hipStream_t stream)
{
    const float* seqs = (const float*)d_in[0];
    const int*   ends = (const int*)d_in[1];
    const float* eG1 = (const float*)d_in[7],  *eB1 = (const float*)d_in[8];
    const float* eG2 = (const float*)d_in[11], *eB2 = (const float*)d_in[12];
    const float* cG1 = (const float*)d_in[17], *cB1 = (const float*)d_in[18];
    const float* cG2 = (const float*)d_in[21], *cB2 = (const float*)d_in[22];
    float* out = (float*)d_out;

    // ---- workspace (ushort bf16 elements) ----
    ushort_t* ws = (ushort_t*)d_ws;
    const long long SEQROW = (long long)NT * SEGL * DMODEL;    // 409600 (b-stride)
    ushort_t* SEQB = ws;                                       // 26,214,400
    ushort_t* WT   = SEQB + 26214400LL;                        // 6,553,600
    ushort_t* ENC  = WT   + 6553600LL;                         // 26,214,400
    ushort_t* BUF0 = ENC  + 26214400LL;                        // 6,553,600
    ushort_t* QKV  = BUF0 + 6553600LL;                         // 19,660,800 (12800x1536)
    ushort_t* BUF4 = QKV  + 19660800LL;                        // 6,553,600
    ushort_t* BUF1 = BUF4 + 6553600LL;                         // 6,553,600
    ushort_t* BUF2 = BUF1 + 6553600LL;                         // 6,553,600
    ushort_t* MID  = BUF2 + 6553600LL;                         // 26,214,400
    ushort_t* OUTB = MID  + 26214400LL;                        // 1,638,400
    ushort_t* QALL = OUTB + 1638400LL;                         // 24,576,000 (48000x512)
    int*      lens = (int*)(QALL + 24576000LL);

    const ushort_t* eWinT = WT + 0;
    const ushort_t* WQKVe = WT + 262144;      // 1536 x 512
    const ushort_t* eWoT  = WT + 1048576;
    const ushort_t* eF1T  = WT + 1310720;     // 2048 x 512
    const ushort_t* eF2T  = WT + 2359296;     // 512 x 2048
    const ushort_t* cWqT  = WT + 3407872;
    const ushort_t* cKV   = WT + 3670016;     // 1024 x 512
    const ushort_t* cWoT  = WT + 4194304;
    const ushort_t* cF1T  = WT + 4456448;
    const ushort_t* cF2T  = WT + 5505024;

    struct WMap { int src; long long dst; int K, N; };
    const WMap wm[13] = {
        {2,  0,       512, 512},   // eWin
        {3,  262144,  512, 512},   // eWq  -> WQKVe rows 0-511
        {4,  524288,  512, 512},   // eWk  -> rows 512-1023
        {5,  786432,  512, 512},   // eWv  -> rows 1024-1535
        {6,  1048576, 512, 512},   // eWo
        {9,  1310720, 512, 2048},  // eF1
        {10, 2359296, 2048, 512},  // eF2
        {13, 3407872, 512, 512},   // cWq
        {14, 3670016, 512, 512},   // cWk -> cKV rows 0-511
        {15, 3932160, 512, 512},   // cWv -> rows 512-1023
        {16, 4194304, 512, 512},   // cWo
        {19, 4456448, 512, 2048},  // cF1
        {20, 5505024, 2048, 512},  // cF2
    };

    cvt_k<<<12800, 256, 0, stream>>>(seqs, SEQB, 26214400LL);
    for (int w = 0; w < 13; ++w) {
        dim3 g(wm[w].N / 32, wm[w].K / 32);
        wtrans_k<<<g, 256, 0, stream>>>((const float*)d_in[wm[w].src],
                                        WT + wm[w].dst, wm[w].K, wm[w].N);
    }
    lens_k<<<4, 256, 0, stream>>>(ends, lens);

    auto gemmL = [&](const ushort_t* A, int agrp, long long astr, const ushort_t* Bt,
                     ushort_t* C, int M, int N, int K, int relu) {
        dim3 g(N / 128, M / 128);
        mfma_gemm<128, 128, 2, 2><<<g, 256, 0, stream>>>(A, agrp, astr, Bt, C, M, N, K, relu);
    };
    auto gemmS = [&](const ushort_t* A, int agrp, long long astr, const ushort_t* Bt,
                     ushort_t* C, int M, int N, int K, int relu) {
        dim3 g(N / 128, M / 64);
        mfma_gemm<64, 128, 2, 2><<<g, 256, 0, stream>>>(A, agrp, astr, Bt, C, M, N, K, relu);
    };

    // ---------------- Phase 1: all encoders, chunks of G=4 segments ----------
    const int G = 4;
    const int Mc = NB * G * SEGL;   // 12800
    for (int c = 0; c < NT / G; ++c) {
        const int t0 = c * G;
        const ushort_t* Abase = SEQB + (long long)t0 * SEGL * DMODEL;
        ushort_t* ENCc = ENC + (long long)t0 * SEGL * DMODEL;
        gemmL(Abase, G * SEGL, SEQROW, eWinT, BUF0, Mc, 512, 512, 0);
        gemmL(BUF0, Mc, 0, WQKVe, QKV, Mc, 1536, 512, 0);
        attn_mfma_k<<<NB * G * NHEAD, 256, 0, stream>>>(
            QKV, 50LL * 1536, 1536, QKV + 512, QKV + 1024, 50LL * 1536, 1536,
            BUF4, lens, G, t0);
        gemmL(BUF4, Mc, 0, eWoT, BUF1, Mc, 512, 512, 0);
        add_ln_k<false><<<Mc / 4, 256, 0, stream>>>(BUF0, Mc, 0, BUF1, eG1, eB1,
                                                    BUF2, Mc, 0, Mc);
        gemmL(BUF2, Mc, 0, eF1T, MID, Mc, 2048, 512, 1);
        gemmL(MID, Mc, 0, eF2T, BUF1, Mc, 512, 2048, 0);
        add_ln_k<false><<<Mc / 4, 256, 0, stream>>>(BUF2, Mc, 0, BUF1, eG2, eB2,
                                                    ENCc, G * SEGL, SEQROW, Mc);
    }

    // Batched Q projections for ALL phase-2 steps: rows m=(b, t-1, s), t=1..15
    // A row m -> ENC + 25600 + (m/750)*409600 + (m%750)*512
    gemmL(ENC + 25600, 750, SEQROW, cWqT, QALL, 48000, 512, 512, 0);

    // ---------------- Phase 2: 15 sequential connection steps ----------------
    const int Ms = NB * SEGL;   // 3200
    for (int t = 1; t < NT; ++t) {
        const ushort_t* currA = ENC + (long long)t * SEGL * DMODEL; // grouped (50, SEQROW)
        const ushort_t* prevA; int pg; long long ps;
        if (t == 1) { prevA = ENC;  pg = SEGL; ps = SEQROW; }
        else        { prevA = OUTB; pg = Ms;   ps = 0; }
        gemmS(prevA, pg, ps, cKV, QKV, Ms, 1024, 512, 0);          // fused KV
        attn_mfma_k<<<NB * NHEAD, 256, 0, stream>>>(
            QALL + (long long)(t - 1) * 25600, 750LL * 512, 512,
            QKV, QKV + 512, 50LL * 1024, 1024,
            BUF4, nullptr, 1, 0);
        gemmS(BUF4, Ms, 0, cWoT, BUF0, Ms, 512, 512, 0);
        add_ln_k<false><<<Ms / 4, 256, 0, stream>>>(currA, SEGL, SEQROW, BUF0, cG1, cB1,
                                                    BUF2, Ms, 0, Ms);
        gemmS(BUF2, Ms, 0, cF1T, MID, Ms, 2048, 512, 1);
        gemmS(MID, Ms, 0, cF2T, BUF0, Ms, 512, 2048, 0);
        if (t == NT - 1)
            add_ln_k<true><<<Ms / 4, 256, 0, stream>>>(BUF2, Ms, 0, BUF0, cG2, cB2,
                                                       out, Ms, 0, Ms);
        else
            add_ln_k<false><<<Ms / 4, 256, 0, stream>>>(BUF2, Ms, 0, BUF0, cG2, cB2,
                                                        OUTB, Ms, 0, Ms);
    }
}

// Round 5
// 2851.053 us; speedup vs baseline: 4.3449x; 1.1063x over previous
//
#include <hip/hip_runtime.h>

// RecurrentTransformerEncoder on MI355X — round 5: restructured GEMM K-loop
// (double-buffered LDS, one barrier/iter, prefetch overlaps MFMA) +
// coalesced LDS-staged epilogue.
// B=64, T=16, SEG=50, E=D=512, H=8, DH=64, F=2048.

#define NB   64
#define NT   16
#define SEGL 50
#define DMODEL 512
#define DFF  2048
#define NHEAD 8
#define DHEAD 64

typedef unsigned short ushort_t;
typedef __attribute__((ext_vector_type(8))) short bfrag;   // 8 bf16 (4 VGPRs)
typedef __attribute__((ext_vector_type(4))) float ffrag;   // 4 fp32 acc

__device__ __forceinline__ ushort_t f2b(float x) {
    union { float f; unsigned u; } c; c.f = x;
    unsigned r = c.u + 0x7fffu + ((c.u >> 16) & 1u);
    return (ushort_t)(r >> 16);
}

#define GLOAD_LDS16(g, l) __builtin_amdgcn_global_load_lds( \
    (const __attribute__((address_space(1))) void*)(g),      \
    (__attribute__((address_space(3))) void*)(l), 16, 0, 0)

// ---------------------------------------------------------------------------
// MFMA GEMM v2: C[M,N](bf16) = relu?(A[M,K](bf16) @ Bt[N,K](bf16)^T)
// A rows remapped: row m at A + (m/agrp)*astride + (m%agrp)*K.
// Double-buffered LDS; prefetch issued after the barrier so the next
// barrier's vmcnt(0) drain waits on loads that had a full iteration to fly.
// Epilogue: acc -> per-wave LDS tile (stride WN+8) -> uint4 coalesced stores.
// ---------------------------------------------------------------------------
template<int BM, int BN, int WROWS, int WCOLS>
__global__ __launch_bounds__(256) void mfma_gemm(
    const ushort_t* __restrict__ A, int agrp, long long astride,
    const ushort_t* __restrict__ Bt, ushort_t* __restrict__ C,
    int M, int N, int K, int relu)
{
    constexpr int WM = BM / WROWS, WN = BN / WCOLS;
    constexpr int SM = WM / 16, SN = WN / 16;
    constexpr int NSUBA = BM / 16, NSUBB = BN / 16;
    constexpr int NSUB = NSUBA + NSUBB;
    constexpr int SPW = NSUB / 4;            // subtile stage-loads per wave
    constexpr int EST = WN + 8;              // epilogue row stride (shorts)
    constexpr int LDS_KLOOP = 2 * NSUB * 512;
    constexpr int LDS_EPI   = 4 * WM * EST;
    constexpr int LDS_SZ = LDS_KLOOP > LDS_EPI ? LDS_KLOOP : LDS_EPI;
    __shared__ ushort_t lds[LDS_SZ];

    const int tid = threadIdx.x;
    const int wave = tid >> 6, lane = tid & 63;
    const int wrow = wave / WCOLS, wcol = wave % WCOLS;
    const int bm = blockIdx.y * BM, bn = blockIdx.x * BN;
    const int lm = lane & 15, lq = lane >> 4;

    ffrag acc[SM][SN];
#pragma unroll
    for (int i = 0; i < SM; ++i)
#pragma unroll
        for (int j = 0; j < SN; ++j) acc[i][j] = (ffrag){0.f, 0.f, 0.f, 0.f};

    const ushort_t* gptr[SPW];
#pragma unroll
    for (int i = 0; i < SPW; ++i) {
        int s = wave * SPW + i;
        if (s < NSUBA) {
            int m = bm + s * 16 + lm;
            gptr[i] = A + (long long)(m / agrp) * astride
                        + (long long)(m % agrp) * K + lq * 8;
        } else {
            int n = bn + (s - NSUBA) * 16 + lm;
            gptr[i] = Bt + (long long)n * K + lq * 8;
        }
    }

    // preload tile 0 into buffer 0
#pragma unroll
    for (int i = 0; i < SPW; ++i)
        GLOAD_LDS16(gptr[i], &lds[(wave * SPW + i) * 512]);

    const int nk = K >> 5;
    for (int kk = 0; kk < nk; ++kk) {
        __syncthreads();   // drains vmcnt -> buf[kk&1] ready; gates buffer reuse
        if (kk + 1 < nk) {
            const int koff = (kk + 1) << 5;
            const int nb = (kk + 1) & 1;
#pragma unroll
            for (int i = 0; i < SPW; ++i)
                GLOAD_LDS16(gptr[i] + koff,
                            &lds[nb * (NSUB * 512) + (wave * SPW + i) * 512]);
        }
        const ushort_t* lb = &lds[(kk & 1) * (NSUB * 512)];
        bfrag af[SM], bfg[SN];
#pragma unroll
        for (int i = 0; i < SM; ++i)
            af[i] = *(const bfrag*)&lb[(wrow * SM + i) * 512 + lane * 8];
#pragma unroll
        for (int j = 0; j < SN; ++j)
            bfg[j] = *(const bfrag*)&lb[(NSUBA + wcol * SN + j) * 512 + lane * 8];
#pragma unroll
        for (int i = 0; i < SM; ++i)
#pragma unroll
            for (int j = 0; j < SN; ++j)
                acc[i][j] = __builtin_amdgcn_mfma_f32_16x16x32_bf16(
                    af[i], bfg[j], acc[i][j], 0, 0, 0);
    }

    // ---- epilogue: per-wave LDS staging, then coalesced uint4 stores ----
    __syncthreads();   // all ds_reads of final tile done before overwrite
    ushort_t* ep = &lds[wave * WM * EST];
#pragma unroll
    for (int i = 0; i < SM; ++i)
#pragma unroll
        for (int j = 0; j < SN; ++j)
#pragma unroll
            for (int r = 0; r < 4; ++r) {
                int row = i * 16 + lq * 4 + r;
                int col = j * 16 + lm;
                float v = acc[i][j][r];
                if (relu) v = fmaxf(v, 0.f);
                ep[row * EST + col] = f2b(v);
            }
    // wave reads back its own region (in-wave LDS ordering): no barrier needed
    constexpr int CPR = WN / 8;          // uint4 chunks per row
    constexpr int RPI = 64 / CPR;        // rows per iteration (full wave)
    const int lrow = lane / CPR, lcol = (lane % CPR) * 8;
#pragma unroll
    for (int it = 0; it < WM / RPI; ++it) {
        int row = it * RPI + lrow;
        uint4 v = *(const uint4*)&ep[row * EST + lcol];
        long long grow = bm + wrow * WM + row;
        int gcol = bn + wcol * WN + lcol;
        *(uint4*)&C[grow * N + gcol] = v;
    }
}

// ---------------------------------------------------------------------------
// Weight transpose+convert: W[K][N] fp32 -> Wt[N][K] bf16.
// ---------------------------------------------------------------------------
__global__ __launch_bounds__(256) void wtrans_k(
    const float* __restrict__ W, ushort_t* __restrict__ Wt, int K, int N)
{
    __shared__ float t[32][33];
    const int bk = blockIdx.y * 32, bn = blockIdx.x * 32;
    const int tx = threadIdx.x & 31, ty = threadIdx.x >> 5;
    for (int i = ty; i < 32; i += 8)
        t[i][tx] = W[(long long)(bk + i) * N + bn + tx];
    __syncthreads();
    for (int i = ty; i < 32; i += 8)
        Wt[(long long)(bn + i) * K + bk + tx] = f2b(t[tx][i]);
}

__global__ __launch_bounds__(256) void cvt_k(
    const float* __restrict__ in, ushort_t* __restrict__ out, long long n)
{
    long long i = ((long long)blockIdx.x * 256 + threadIdx.x) * 8;
    if (i >= n) return;
    float4 a = *(const float4*)(in + i);
    float4 b = *(const float4*)(in + i + 4);
    ushort_t o[8] = {f2b(a.x), f2b(a.y), f2b(a.z), f2b(a.w),
                     f2b(b.x), f2b(b.y), f2b(b.z), f2b(b.w)};
    *(uint4*)(out + i) = *(const uint4*)o;
}

// ---------------------------------------------------------------------------
// MFMA attention, one (sequence n, head h) per block. S=50->64 pad, D=64.
// ---------------------------------------------------------------------------
__global__ __launch_bounds__(256) void attn_mfma_k(
    const ushort_t* __restrict__ Q, long long qns, long long qrs,
    const ushort_t* __restrict__ K, const ushort_t* __restrict__ V,
    long long kns, long long kvrs,
    ushort_t* __restrict__ O,
    const int* __restrict__ lens, int G, int t0)
{
    __shared__ ushort_t qs[64][72];   // Q, then P
    __shared__ ushort_t ks[64][72];
    __shared__ ushort_t vt[64][72];   // V^T: vt[d][j]
    const int n = blockIdx.x >> 3, h = blockIdx.x & 7;
    const int tid = threadIdx.x;
    const int wave = tid >> 6, lane = tid & 63;
    const int lm = lane & 15, lq = lane >> 4;
    int len = SEGL;
    if (lens) {
        int b = n / G, t = t0 + (n % G);
        len = lens[b * NT + t];
        if (len > SEGL) len = SEGL;
    }
    {
        uint4 z = {0, 0, 0, 0};
        uint4* vz = (uint4*)&vt[0][0];
        for (int i = tid; i < 64 * 72 / 8; i += 256) vz[i] = z;
    }
    __syncthreads();
    for (int idx = tid; idx < SEGL * 8; idx += 256) {
        int s = idx >> 3, d8 = (idx & 7) << 3;
        const ushort_t* qp = Q + (long long)n * qns + (long long)s * qrs + h * DHEAD + d8;
        const ushort_t* kp = K + (long long)n * kns + (long long)s * kvrs + h * DHEAD + d8;
        const ushort_t* vp = V + (long long)n * kns + (long long)s * kvrs + h * DHEAD + d8;
        *(uint4*)&qs[s][d8] = *(const uint4*)qp;
        *(uint4*)&ks[s][d8] = *(const uint4*)kp;
        uint4 v4 = *(const uint4*)vp;
        const ushort_t* vv = (const ushort_t*)&v4;
#pragma unroll
        for (int u = 0; u < 8; ++u) vt[d8 + u][s] = vv[u];
    }
    __syncthreads();

    ffrag sc[4];
#pragma unroll
    for (int nt = 0; nt < 4; ++nt) sc[nt] = (ffrag){0.f, 0.f, 0.f, 0.f};
#pragma unroll
    for (int kt = 0; kt < 2; ++kt) {
        bfrag a = *(const bfrag*)&qs[wave * 16 + lm][kt * 32 + lq * 8];
#pragma unroll
        for (int nt = 0; nt < 4; ++nt) {
            bfrag b = *(const bfrag*)&ks[nt * 16 + lm][kt * 32 + lq * 8];
            sc[nt] = __builtin_amdgcn_mfma_f32_16x16x32_bf16(a, b, sc[nt], 0, 0, 0);
        }
    }
    __syncthreads();

#pragma unroll
    for (int r = 0; r < 4; ++r) {
        float x[4];
        float mx = -1e30f;
#pragma unroll
        for (int nt = 0; nt < 4; ++nt) {
            int col = nt * 16 + lm;
            x[nt] = (col < len) ? sc[nt][r] * 0.125f : -1e9f;
            mx = fmaxf(mx, x[nt]);
        }
        for (int off = 8; off; off >>= 1) mx = fmaxf(mx, __shfl_xor(mx, off));
        float e[4], se = 0.f;
#pragma unroll
        for (int nt = 0; nt < 4; ++nt) { e[nt] = __expf(x[nt] - mx); se += e[nt]; }
        for (int off = 8; off; off >>= 1) se += __shfl_xor(se, off);
        float inv = 1.f / se;
        int row = wave * 16 + lq * 4 + r;
#pragma unroll
        for (int nt = 0; nt < 4; ++nt)
            qs[row][nt * 16 + lm] = f2b(e[nt] * inv);
    }
    __syncthreads();

    ffrag oc[4];
#pragma unroll
    for (int dt = 0; dt < 4; ++dt) oc[dt] = (ffrag){0.f, 0.f, 0.f, 0.f};
#pragma unroll
    for (int kt = 0; kt < 2; ++kt) {
        bfrag a = *(const bfrag*)&qs[wave * 16 + lm][kt * 32 + lq * 8];
#pragma unroll
        for (int dt = 0; dt < 4; ++dt) {
            bfrag b = *(const bfrag*)&vt[dt * 16 + lm][kt * 32 + lq * 8];
            oc[dt] = __builtin_amdgcn_mfma_f32_16x16x32_bf16(a, b, oc[dt], 0, 0, 0);
        }
    }
#pragma unroll
    for (int r = 0; r < 4; ++r) {
        int i = wave * 16 + lq * 4 + r;
        if (i < SEGL) {
            ushort_t* op = O + (long long)(n * SEGL + i) * DMODEL + h * DHEAD + lm;
#pragma unroll
            for (int dt = 0; dt < 4; ++dt)
                op[dt * 16] = f2b(oc[dt][r]);
        }
    }
}

// ---------------------------------------------------------------------------
// out = LN(a + b)*gamma + beta, rows of 512, bf16 in, bf16/fp32 out.
// ---------------------------------------------------------------------------
template<bool OUTF32>
__global__ __launch_bounds__(256) void add_ln_k(
    const ushort_t* __restrict__ A, int agrp, long long astride,
    const ushort_t* __restrict__ Bv,
    const float* __restrict__ gamma, const float* __restrict__ beta,
    void* __restrict__ O, int ogrp, long long ostride, int M)
{
    const int wave = threadIdx.x >> 6, lane = threadIdx.x & 63;
    const int r = blockIdx.x * 4 + wave;
    if (r >= M) return;
    const ushort_t* a = A + (long long)(r / agrp) * astride + (long long)(r % agrp) * DMODEL;
    const ushort_t* b = Bv + (long long)r * DMODEL;
    float x[8];
    {
        uint4 a4 = *(const uint4*)(a + lane * 8);
        uint4 b4 = *(const uint4*)(b + lane * 8);
        const unsigned* aa = (const unsigned*)&a4;
        const unsigned* bb = (const unsigned*)&b4;
#pragma unroll
        for (int c = 0; c < 4; ++c) {
            union { unsigned u; float f; } alo, ahi, blo, bhi;
            alo.u = aa[c] << 16; ahi.u = aa[c] & 0xffff0000u;
            blo.u = bb[c] << 16; bhi.u = bb[c] & 0xffff0000u;
            x[2 * c]     = alo.f + blo.f;
            x[2 * c + 1] = ahi.f + bhi.f;
        }
    }
    float s = 0.f, s2 = 0.f;
#pragma unroll
    for (int i = 0; i < 8; ++i) { s += x[i]; s2 = fmaf(x[i], x[i], s2); }
    for (int off = 32; off; off >>= 1) {
        s += __shfl_xor(s, off);
        s2 += __shfl_xor(s2, off);
    }
    const float mean = s * (1.f / DMODEL);
    const float var = s2 * (1.f / DMODEL) - mean * mean;
    const float inv = rsqrtf(var + 1e-5f);
    float4 g0 = *(const float4*)(gamma + lane * 8);
    float4 g1 = *(const float4*)(gamma + lane * 8 + 4);
    float4 be0 = *(const float4*)(beta + lane * 8);
    float4 be1 = *(const float4*)(beta + lane * 8 + 4);
    float y[8];
    y[0] = (x[0] - mean) * inv * g0.x + be0.x;
    y[1] = (x[1] - mean) * inv * g0.y + be0.y;
    y[2] = (x[2] - mean) * inv * g0.z + be0.z;
    y[3] = (x[3] - mean) * inv * g0.w + be0.w;
    y[4] = (x[4] - mean) * inv * g1.x + be1.x;
    y[5] = (x[5] - mean) * inv * g1.y + be1.y;
    y[6] = (x[6] - mean) * inv * g1.z + be1.z;
    y[7] = (x[7] - mean) * inv * g1.w + be1.w;
    if (OUTF32) {
        float* o = (float*)O + (long long)(r / ogrp) * ostride + (long long)(r % ogrp) * DMODEL;
        *(float4*)(o + lane * 8) = *(float4*)&y[0];
        *(float4*)(o + lane * 8 + 4) = *(float4*)&y[4];
    } else {
        ushort_t* o = (ushort_t*)O + (long long)(r / ogrp) * ostride + (long long)(r % ogrp) * DMODEL;
        ushort_t ob[8];
#pragma unroll
        for (int i = 0; i < 8; ++i) ob[i] = f2b(y[i]);
        *(uint4*)(o + lane * 8) = *(const uint4*)ob;
    }
}

__global__ void lens_k(const int* __restrict__ ends, int* __restrict__ lens)
{
    int i = blockIdx.x * 256 + threadIdx.x;
    if (i >= NB * NT) return;
    int t = i & (NT - 1);
    int prev = t ? ends[i - 1] : 0;
    int l = ends[i] - prev;
    if (l > SEGL) l = SEGL;
    lens[i] = l;
}

// ---------------------------------------------------------------------------
extern "C" void kernel_launch(void* const* d_in, const int* in_sizes, int n_in,
                              void* d_out, int out_size, void* d_ws, size_t ws_size,
                              hipStream_t stream)
{
    const float* seqs = (const float*)d_in[0];
    const int*   ends = (const int*)d_in[1];
    const float* eG1 = (const float*)d_in[7],  *eB1 = (const float*)d_in[8];
    const float* eG2 = (const float*)d_in[11], *eB2 = (const float*)d_in[12];
    const float* cG1 = (const float*)d_in[17], *cB1 = (const float*)d_in[18];
    const float* cG2 = (const float*)d_in[21], *cB2 = (const float*)d_in[22];
    float* out = (float*)d_out;

    // ---- workspace (ushort bf16 elements) ----
    ushort_t* ws = (ushort_t*)d_ws;
    const long long SEQROW = (long long)NT * SEGL * DMODEL;    // 409600 (b-stride)
    ushort_t* SEQB = ws;                                       // 26,214,400
    ushort_t* WT   = SEQB + 26214400LL;                        // 6,553,600
    ushort_t* ENC  = WT   + 6553600LL;                         // 26,214,400
    ushort_t* BUF0 = ENC  + 26214400LL;                        // 6,553,600
    ushort_t* QKV  = BUF0 + 6553600LL;                         // 19,660,800 (12800x1536)
    ushort_t* BUF4 = QKV  + 19660800LL;                        // 6,553,600
    ushort_t* BUF1 = BUF4 + 6553600LL;                         // 6,553,600
    ushort_t* BUF2 = BUF1 + 6553600LL;                         // 6,553,600
    ushort_t* MID  = BUF2 + 6553600LL;                         // 26,214,400
    ushort_t* OUTB = MID  + 26214400LL;                        // 1,638,400
    ushort_t* QALL = OUTB + 1638400LL;                         // 24,576,000 (48000x512)
    int*      lens = (int*)(QALL + 24576000LL);

    const ushort_t* eWinT = WT + 0;
    const ushort_t* WQKVe = WT + 262144;      // 1536 x 512
    const ushort_t* eWoT  = WT + 1048576;
    const ushort_t* eF1T  = WT + 1310720;     // 2048 x 512
    const ushort_t* eF2T  = WT + 2359296;     // 512 x 2048
    const ushort_t* cWqT  = WT + 3407872;
    const ushort_t* cKV   = WT + 3670016;     // 1024 x 512
    const ushort_t* cWoT  = WT + 4194304;
    const ushort_t* cF1T  = WT + 4456448;
    const ushort_t* cF2T  = WT + 5505024;

    struct WMap { int src; long long dst; int K, N; };
    const WMap wm[13] = {
        {2,  0,       512, 512},   // eWin
        {3,  262144,  512, 512},   // eWq  -> WQKVe rows 0-511
        {4,  524288,  512, 512},   // eWk  -> rows 512-1023
        {5,  786432,  512, 512},   // eWv  -> rows 1024-1535
        {6,  1048576, 512, 512},   // eWo
        {9,  1310720, 512, 2048},  // eF1
        {10, 2359296, 2048, 512},  // eF2
        {13, 3407872, 512, 512},   // cWq
        {14, 3670016, 512, 512},   // cWk -> cKV rows 0-511
        {15, 3932160, 512, 512},   // cWv -> rows 512-1023
        {16, 4194304, 512, 512},   // cWo
        {19, 4456448, 512, 2048},  // cF1
        {20, 5505024, 2048, 512},  // cF2
    };

    cvt_k<<<12800, 256, 0, stream>>>(seqs, SEQB, 26214400LL);
    for (int w = 0; w < 13; ++w) {
        dim3 g(wm[w].N / 32, wm[w].K / 32);
        wtrans_k<<<g, 256, 0, stream>>>((const float*)d_in[wm[w].src],
                                        WT + wm[w].dst, wm[w].K, wm[w].N);
    }
    lens_k<<<4, 256, 0, stream>>>(ends, lens);

    auto gemmL = [&](const ushort_t* A, int agrp, long long astr, const ushort_t* Bt,
                     ushort_t* C, int M, int N, int K, int relu) {
        dim3 g(N / 128, M / 128);
        mfma_gemm<128, 128, 2, 2><<<g, 256, 0, stream>>>(A, agrp, astr, Bt, C, M, N, K, relu);
    };
    auto gemmS = [&](const ushort_t* A, int agrp, long long astr, const ushort_t* Bt,
                     ushort_t* C, int M, int N, int K, int relu) {
        dim3 g(N / 128, M / 64);
        mfma_gemm<64, 128, 2, 2><<<g, 256, 0, stream>>>(A, agrp, astr, Bt, C, M, N, K, relu);
    };

    // ---------------- Phase 1: all encoders, chunks of G=4 segments ----------
    const int G = 4;
    const int Mc = NB * G * SEGL;   // 12800
    for (int c = 0; c < NT / G; ++c) {
        const int t0 = c * G;
        const ushort_t* Abase = SEQB + (long long)t0 * SEGL * DMODEL;
        ushort_t* ENCc = ENC + (long long)t0 * SEGL * DMODEL;
        gemmL(Abase, G * SEGL, SEQROW, eWinT, BUF0, Mc, 512, 512, 0);
        gemmL(BUF0, Mc, 0, WQKVe, QKV, Mc, 1536, 512, 0);
        attn_mfma_k<<<NB * G * NHEAD, 256, 0, stream>>>(
            QKV, 50LL * 1536, 1536, QKV + 512, QKV + 1024, 50LL * 1536, 1536,
            BUF4, lens, G, t0);
        gemmL(BUF4, Mc, 0, eWoT, BUF1, Mc, 512, 512, 0);
        add_ln_k<false><<<Mc / 4, 256, 0, stream>>>(BUF0, Mc, 0, BUF1, eG1, eB1,
                                                    BUF2, Mc, 0, Mc);
        gemmL(BUF2, Mc, 0, eF1T, MID, Mc, 2048, 512, 1);
        gemmL(MID, Mc, 0, eF2T, BUF1, Mc, 512, 2048, 0);
        add_ln_k<false><<<Mc / 4, 256, 0, stream>>>(BUF2, Mc, 0, BUF1, eG2, eB2,
                                                    ENCc, G * SEGL, SEQROW, Mc);
    }

    // Batched Q projections for ALL phase-2 steps: rows m=(b, t-1, s), t=1..15
    gemmL(ENC + 25600, 750, SEQROW, cWqT, QALL, 48000, 512, 512, 0);

    // ---------------- Phase 2: 15 sequential connection steps ----------------
    const int Ms = NB * SEGL;   // 3200
    for (int t = 1; t < NT; ++t) {
        const ushort_t* currA = ENC + (long long)t * SEGL * DMODEL; // grouped (50, SEQROW)
        const ushort_t* prevA; int pg; long long ps;
        if (t == 1) { prevA = ENC;  pg = SEGL; ps = SEQROW; }
        else        { prevA = OUTB; pg = Ms;   ps = 0; }
        gemmS(prevA, pg, ps, cKV, QKV, Ms, 1024, 512, 0);          // fused KV
        attn_mfma_k<<<NB * NHEAD, 256, 0, stream>>>(
            QALL + (long long)(t - 1) * 25600, 750LL * 512, 512,
            QKV, QKV + 512, 50LL * 1024, 1024,
            BUF4, nullptr, 1, 0);
        gemmS(BUF4, Ms, 0, cWoT, BUF0, Ms, 512, 512, 0);
        add_ln_k<false><<<Ms / 4, 256, 0, stream>>>(currA, SEGL, SEQROW, BUF0, cG1, cB1,
                                                    BUF2, Ms, 0, Ms);
        gemmS(BUF2, Ms, 0, cF1T, MID, Ms, 2048, 512, 1);
        gemmS(MID, Ms, 0, cF2T, BUF0, Ms, 512, 2048, 0);
        if (t == NT - 1)
            add_ln_k<true><<<Ms / 4, 256, 0, stream>>>(BUF2, Ms, 0, BUF0, cG2, cB2,
                                                       out, Ms, 0, Ms);
        else
            add_ln_k<false><<<Ms / 4, 256, 0, stream>>>(BUF2, Ms, 0, BUF0, cG2, cB2,
                                                        OUTB, Ms, 0, Ms);
    }
}

// Round 6
// 2845.453 us; speedup vs baseline: 4.3535x; 1.0020x over previous
//
#include <hip/hip_runtime.h>

// RecurrentTransformerEncoder on MI355X — round 6: BK=64 K-loop (half the
// barriers, 2x prefetch slack) + full/8-seg batched phase-1 (ws_size-gated).
// B=64, T=16, SEG=50, E=D=512, H=8, DH=64, F=2048.

#define NB   64
#define NT   16
#define SEGL 50
#define DMODEL 512
#define DFF  2048
#define NHEAD 8
#define DHEAD 64

typedef unsigned short ushort_t;
typedef __attribute__((ext_vector_type(8))) short bfrag;   // 8 bf16 (4 VGPRs)
typedef __attribute__((ext_vector_type(4))) float ffrag;   // 4 fp32 acc

__device__ __forceinline__ ushort_t f2b(float x) {
    union { float f; unsigned u; } c; c.f = x;
    unsigned r = c.u + 0x7fffu + ((c.u >> 16) & 1u);
    return (ushort_t)(r >> 16);
}

#define GLOAD_LDS16(g, l) __builtin_amdgcn_global_load_lds( \
    (const __attribute__((address_space(1))) void*)(g),      \
    (__attribute__((address_space(3))) void*)(l), 16, 0, 0)

// ---------------------------------------------------------------------------
// MFMA GEMM v3: C[M,N](bf16) = relu?(A[M,K](bf16) @ Bt[N,K](bf16)^T)
// A rows remapped: row m at A + (m/agrp)*astride + (m%agrp)*K.
// BK=64 double-buffered LDS: 8 barriers at K=512 instead of 16; the
// prefetch issued after barrier k is drained at barrier k+1, i.e. after a
// full 64-K MFMA body (~600 cyc) — covers HBM-class latency.
// Subtile = 16 rows x 64 k = 1024 shorts, stored as two 512-short fragment
// halves (each one global_load_lds_dwordx4 per wave).
// Epilogue: acc -> per-wave LDS tile -> coalesced uint4 stores.
// ---------------------------------------------------------------------------
template<int BM, int BN, int WROWS, int WCOLS>
__global__ __launch_bounds__(256) void mfma_gemm(
    const ushort_t* __restrict__ A, int agrp, long long astride,
    const ushort_t* __restrict__ Bt, ushort_t* __restrict__ C,
    int M, int N, int K, int relu)
{
    constexpr int WM = BM / WROWS, WN = BN / WCOLS;
    constexpr int SM = WM / 16, SN = WN / 16;
    constexpr int NSUBA = BM / 16, NSUBB = BN / 16;
    constexpr int NSUB = NSUBA + NSUBB;          // subtiles of 16 rows x 64 k
    constexpr int NINST = NSUB * 2;              // 1KB stage-instructions/block
    constexpr int IPW = NINST / 4;               // per wave
    constexpr int BUFS = NSUB * 1024;            // shorts per buffer
    constexpr int EST = WN + 8;                  // epilogue row stride (shorts)
    constexpr int LDS_KLOOP = 2 * BUFS;
    constexpr int LDS_EPI   = 4 * WM * EST;
    constexpr int LDS_SZ = LDS_KLOOP > LDS_EPI ? LDS_KLOOP : LDS_EPI;
    __shared__ ushort_t lds[LDS_SZ];

    const int tid = threadIdx.x;
    const int wave = tid >> 6, lane = tid & 63;
    const int wrow = wave / WCOLS, wcol = wave % WCOLS;
    const int bm = blockIdx.y * BM, bn = blockIdx.x * BN;
    const int lm = lane & 15, lq = lane >> 4;

    ffrag acc[SM][SN];
#pragma unroll
    for (int i = 0; i < SM; ++i)
#pragma unroll
        for (int j = 0; j < SN; ++j) acc[i][j] = (ffrag){0.f, 0.f, 0.f, 0.f};

    // stage instruction e: subtile s = e>>1, k-half h = e&1.
    const ushort_t* gptr[IPW];
    int loff[IPW];
#pragma unroll
    for (int e = 0; e < IPW; ++e) {
        int g = wave * IPW + e;
        int s = g >> 1, h = g & 1;
        if (s < NSUBA) {
            int m = bm + s * 16 + lm;
            gptr[e] = A + (long long)(m / agrp) * astride
                        + (long long)(m % agrp) * K + h * 32 + lq * 8;
        } else {
            int n = bn + (s - NSUBA) * 16 + lm;
            gptr[e] = Bt + (long long)n * K + h * 32 + lq * 8;
        }
        loff[e] = s * 1024 + h * 512;
    }

    // preload tile 0 into buffer 0
#pragma unroll
    for (int e = 0; e < IPW; ++e)
        GLOAD_LDS16(gptr[e], &lds[loff[e]]);

    const int nk = K >> 6;
    for (int kk = 0; kk < nk; ++kk) {
        __syncthreads();   // drains vmcnt: buf[kk&1] ready; gates buffer reuse
        if (kk + 1 < nk) {
            const int koff = (kk + 1) << 6;
            const int nb = (kk + 1) & 1;
#pragma unroll
            for (int e = 0; e < IPW; ++e)
                GLOAD_LDS16(gptr[e] + koff, &lds[nb * BUFS + loff[e]]);
        }
        const ushort_t* lb = &lds[(kk & 1) * BUFS];
#pragma unroll
        for (int h = 0; h < 2; ++h) {
            bfrag af[SM], bfg[SN];
#pragma unroll
            for (int i = 0; i < SM; ++i)
                af[i] = *(const bfrag*)&lb[(wrow * SM + i) * 1024 + h * 512 + lane * 8];
#pragma unroll
            for (int j = 0; j < SN; ++j)
                bfg[j] = *(const bfrag*)&lb[(NSUBA + wcol * SN + j) * 1024 + h * 512 + lane * 8];
#pragma unroll
            for (int i = 0; i < SM; ++i)
#pragma unroll
                for (int j = 0; j < SN; ++j)
                    acc[i][j] = __builtin_amdgcn_mfma_f32_16x16x32_bf16(
                        af[i], bfg[j], acc[i][j], 0, 0, 0);
        }
    }

    // ---- epilogue: per-wave LDS staging, then coalesced uint4 stores ----
    __syncthreads();
    ushort_t* ep = &lds[wave * WM * EST];
#pragma unroll
    for (int i = 0; i < SM; ++i)
#pragma unroll
        for (int j = 0; j < SN; ++j)
#pragma unroll
            for (int r = 0; r < 4; ++r) {
                int row = i * 16 + lq * 4 + r;
                int col = j * 16 + lm;
                float v = acc[i][j][r];
                if (relu) v = fmaxf(v, 0.f);
                ep[row * EST + col] = f2b(v);
            }
    constexpr int CPR = WN / 8;
    constexpr int RPI = 64 / CPR;
    const int lrow = lane / CPR, lcol = (lane % CPR) * 8;
#pragma unroll
    for (int it = 0; it < WM / RPI; ++it) {
        int row = it * RPI + lrow;
        uint4 v = *(const uint4*)&ep[row * EST + lcol];
        long long grow = bm + wrow * WM + row;
        int gcol = bn + wcol * WN + lcol;
        *(uint4*)&C[grow * N + gcol] = v;
    }
}

// ---------------------------------------------------------------------------
__global__ __launch_bounds__(256) void wtrans_k(
    const float* __restrict__ W, ushort_t* __restrict__ Wt, int K, int N)
{
    __shared__ float t[32][33];
    const int bk = blockIdx.y * 32, bn = blockIdx.x * 32;
    const int tx = threadIdx.x & 31, ty = threadIdx.x >> 5;
    for (int i = ty; i < 32; i += 8)
        t[i][tx] = W[(long long)(bk + i) * N + bn + tx];
    __syncthreads();
    for (int i = ty; i < 32; i += 8)
        Wt[(long long)(bn + i) * K + bk + tx] = f2b(t[tx][i]);
}

__global__ __launch_bounds__(256) void cvt_k(
    const float* __restrict__ in, ushort_t* __restrict__ out, long long n)
{
    long long i = ((long long)blockIdx.x * 256 + threadIdx.x) * 8;
    if (i >= n) return;
    float4 a = *(const float4*)(in + i);
    float4 b = *(const float4*)(in + i + 4);
    ushort_t o[8] = {f2b(a.x), f2b(a.y), f2b(a.z), f2b(a.w),
                     f2b(b.x), f2b(b.y), f2b(b.z), f2b(b.w)};
    *(uint4*)(out + i) = *(const uint4*)o;
}

// ---------------------------------------------------------------------------
// MFMA attention, one (sequence n, head h) per block. S=50->64 pad, D=64.
// ---------------------------------------------------------------------------
__global__ __launch_bounds__(256) void attn_mfma_k(
    const ushort_t* __restrict__ Q, long long qns, long long qrs,
    const ushort_t* __restrict__ K, const ushort_t* __restrict__ V,
    long long kns, long long kvrs,
    ushort_t* __restrict__ O,
    const int* __restrict__ lens, int G, int t0)
{
    __shared__ ushort_t qs[64][72];   // Q, then P
    __shared__ ushort_t ks[64][72];
    __shared__ ushort_t vt[64][72];   // V^T: vt[d][j]
    const int n = blockIdx.x >> 3, h = blockIdx.x & 7;
    const int tid = threadIdx.x;
    const int wave = tid >> 6, lane = tid & 63;
    const int lm = lane & 15, lq = lane >> 4;
    int len = SEGL;
    if (lens) {
        int b = n / G, t = t0 + (n % G);
        len = lens[b * NT + t];
        if (len > SEGL) len = SEGL;
    }
    {
        uint4 z = {0, 0, 0, 0};
        uint4* vz = (uint4*)&vt[0][0];
        for (int i = tid; i < 64 * 72 / 8; i += 256) vz[i] = z;
    }
    __syncthreads();
    for (int idx = tid; idx < SEGL * 8; idx += 256) {
        int s = idx >> 3, d8 = (idx & 7) << 3;
        const ushort_t* qp = Q + (long long)n * qns + (long long)s * qrs + h * DHEAD + d8;
        const ushort_t* kp = K + (long long)n * kns + (long long)s * kvrs + h * DHEAD + d8;
        const ushort_t* vp = V + (long long)n * kns + (long long)s * kvrs + h * DHEAD + d8;
        *(uint4*)&qs[s][d8] = *(const uint4*)qp;
        *(uint4*)&ks[s][d8] = *(const uint4*)kp;
        uint4 v4 = *(const uint4*)vp;
        const ushort_t* vv = (const ushort_t*)&v4;
#pragma unroll
        for (int u = 0; u < 8; ++u) vt[d8 + u][s] = vv[u];
    }
    __syncthreads();

    ffrag sc[4];
#pragma unroll
    for (int nt = 0; nt < 4; ++nt) sc[nt] = (ffrag){0.f, 0.f, 0.f, 0.f};
#pragma unroll
    for (int kt = 0; kt < 2; ++kt) {
        bfrag a = *(const bfrag*)&qs[wave * 16 + lm][kt * 32 + lq * 8];
#pragma unroll
        for (int nt = 0; nt < 4; ++nt) {
            bfrag b = *(const bfrag*)&ks[nt * 16 + lm][kt * 32 + lq * 8];
            sc[nt] = __builtin_amdgcn_mfma_f32_16x16x32_bf16(a, b, sc[nt], 0, 0, 0);
        }
    }
    __syncthreads();

#pragma unroll
    for (int r = 0; r < 4; ++r) {
        float x[4];
        float mx = -1e30f;
#pragma unroll
        for (int nt = 0; nt < 4; ++nt) {
            int col = nt * 16 + lm;
            x[nt] = (col < len) ? sc[nt][r] * 0.125f : -1e9f;
            mx = fmaxf(mx, x[nt]);
        }
        for (int off = 8; off; off >>= 1) mx = fmaxf(mx, __shfl_xor(mx, off));
        float e[4], se = 0.f;
#pragma unroll
        for (int nt = 0; nt < 4; ++nt) { e[nt] = __expf(x[nt] - mx); se += e[nt]; }
        for (int off = 8; off; off >>= 1) se += __shfl_xor(se, off);
        float inv = 1.f / se;
        int row = wave * 16 + lq * 4 + r;
#pragma unroll
        for (int nt = 0; nt < 4; ++nt)
            qs[row][nt * 16 + lm] = f2b(e[nt] * inv);
    }
    __syncthreads();

    ffrag oc[4];
#pragma unroll
    for (int dt = 0; dt < 4; ++dt) oc[dt] = (ffrag){0.f, 0.f, 0.f, 0.f};
#pragma unroll
    for (int kt = 0; kt < 2; ++kt) {
        bfrag a = *(const bfrag*)&qs[wave * 16 + lm][kt * 32 + lq * 8];
#pragma unroll
        for (int dt = 0; dt < 4; ++dt) {
            bfrag b = *(const bfrag*)&vt[dt * 16 + lm][kt * 32 + lq * 8];
            oc[dt] = __builtin_amdgcn_mfma_f32_16x16x32_bf16(a, b, oc[dt], 0, 0, 0);
        }
    }
#pragma unroll
    for (int r = 0; r < 4; ++r) {
        int i = wave * 16 + lq * 4 + r;
        if (i < SEGL) {
            ushort_t* op = O + (long long)(n * SEGL + i) * DMODEL + h * DHEAD + lm;
#pragma unroll
            for (int dt = 0; dt < 4; ++dt)
                op[dt * 16] = f2b(oc[dt][r]);
        }
    }
}

// ---------------------------------------------------------------------------
// out = LN(a + b)*gamma + beta, rows of 512, bf16 in, bf16/fp32 out.
// ---------------------------------------------------------------------------
template<bool OUTF32>
__global__ __launch_bounds__(256) void add_ln_k(
    const ushort_t* __restrict__ A, int agrp, long long astride,
    const ushort_t* __restrict__ Bv,
    const float* __restrict__ gamma, const float* __restrict__ beta,
    void* __restrict__ O, int ogrp, long long ostride, int M)
{
    const int wave = threadIdx.x >> 6, lane = threadIdx.x & 63;
    const int r = blockIdx.x * 4 + wave;
    if (r >= M) return;
    const ushort_t* a = A + (long long)(r / agrp) * astride + (long long)(r % agrp) * DMODEL;
    const ushort_t* b = Bv + (long long)r * DMODEL;
    float x[8];
    {
        uint4 a4 = *(const uint4*)(a + lane * 8);
        uint4 b4 = *(const uint4*)(b + lane * 8);
        const unsigned* aa = (const unsigned*)&a4;
        const unsigned* bb = (const unsigned*)&b4;
#pragma unroll
        for (int c = 0; c < 4; ++c) {
            union { unsigned u; float f; } alo, ahi, blo, bhi;
            alo.u = aa[c] << 16; ahi.u = aa[c] & 0xffff0000u;
            blo.u = bb[c] << 16; bhi.u = bb[c] & 0xffff0000u;
            x[2 * c]     = alo.f + blo.f;
            x[2 * c + 1] = ahi.f + bhi.f;
        }
    }
    float s = 0.f, s2 = 0.f;
#pragma unroll
    for (int i = 0; i < 8; ++i) { s += x[i]; s2 = fmaf(x[i], x[i], s2); }
    for (int off = 32; off; off >>= 1) {
        s += __shfl_xor(s, off);
        s2 += __shfl_xor(s2, off);
    }
    const float mean = s * (1.f / DMODEL);
    const float var = s2 * (1.f / DMODEL) - mean * mean;
    const float inv = rsqrtf(var + 1e-5f);
    float4 g0 = *(const float4*)(gamma + lane * 8);
    float4 g1 = *(const float4*)(gamma + lane * 8 + 4);
    float4 be0 = *(const float4*)(beta + lane * 8);
    float4 be1 = *(const float4*)(beta + lane * 8 + 4);
    float y[8];
    y[0] = (x[0] - mean) * inv * g0.x + be0.x;
    y[1] = (x[1] - mean) * inv * g0.y + be0.y;
    y[2] = (x[2] - mean) * inv * g0.z + be0.z;
    y[3] = (x[3] - mean) * inv * g0.w + be0.w;
    y[4] = (x[4] - mean) * inv * g1.x + be1.x;
    y[5] = (x[5] - mean) * inv * g1.y + be1.y;
    y[6] = (x[6] - mean) * inv * g1.z + be1.z;
    y[7] = (x[7] - mean) * inv * g1.w + be1.w;
    if (OUTF32) {
        float* o = (float*)O + (long long)(r / ogrp) * ostride + (long long)(r % ogrp) * DMODEL;
        *(float4*)(o + lane * 8) = *(float4*)&y[0];
        *(float4*)(o + lane * 8 + 4) = *(float4*)&y[4];
    } else {
        ushort_t* o = (ushort_t*)O + (long long)(r / ogrp) * ostride + (long long)(r % ogrp) * DMODEL;
        ushort_t ob[8];
#pragma unroll
        for (int i = 0; i < 8; ++i) ob[i] = f2b(y[i]);
        *(uint4*)(o + lane * 8) = *(const uint4*)ob;
    }
}

__global__ void lens_k(const int* __restrict__ ends, int* __restrict__ lens)
{
    int i = blockIdx.x * 256 + threadIdx.x;
    if (i >= NB * NT) return;
    int t = i & (NT - 1);
    int prev = t ? ends[i - 1] : 0;
    int l = ends[i] - prev;
    if (l > SEGL) l = SEGL;
    lens[i] = l;
}

// ---------------------------------------------------------------------------
extern "C" void kernel_launch(void* const* d_in, const int* in_sizes, int n_in,
                              void* d_out, int out_size, void* d_ws, size_t ws_size,
                              hipStream_t stream)
{
    const float* seqs = (const float*)d_in[0];
    const int*   ends = (const int*)d_in[1];
    const float* eG1 = (const float*)d_in[7],  *eB1 = (const float*)d_in[8];
    const float* eG2 = (const float*)d_in[11], *eB2 = (const float*)d_in[12];
    const float* cG1 = (const float*)d_in[17], *cB1 = (const float*)d_in[18];
    const float* cG2 = (const float*)d_in[21], *cB2 = (const float*)d_in[22];
    float* out = (float*)d_out;

    // Phase-1 chunk size: G=8 needs ~459 MB; fall back to G=4 (~315 MB).
    const int G = (ws_size >= (size_t)470000000) ? 8 : 4;
    const long long CH = 1638400LL * G;   // rows*512 per chunk buffer

    // ---- workspace (ushort bf16 elements) ----
    ushort_t* ws = (ushort_t*)d_ws;
    const long long SEQROW = (long long)NT * SEGL * DMODEL;    // 409600 (b-stride)
    ushort_t* SEQB = ws;                                       // 26,214,400
    ushort_t* WT   = SEQB + 26214400LL;                        // 6,553,600
    ushort_t* ENC  = WT   + 6553600LL;                         // 26,214,400
    ushort_t* BUF0 = ENC  + 26214400LL;                        // CH
    ushort_t* QKV  = BUF0 + CH;                                // 3*CH
    ushort_t* BUF4 = QKV  + 3 * CH;                            // CH
    ushort_t* BUF1 = BUF4 + CH;                                // CH
    ushort_t* BUF2 = BUF1 + CH;                                // CH
    ushort_t* MID  = BUF2 + CH;                                // 4*CH
    ushort_t* OUTB = MID  + 4 * CH;                            // 1,638,400
    ushort_t* QALL = OUTB + 1638400LL;                         // 24,576,000
    int*      lens = (int*)(QALL + 24576000LL);

    const ushort_t* eWinT = WT + 0;
    const ushort_t* WQKVe = WT + 262144;      // 1536 x 512
    const ushort_t* eWoT  = WT + 1048576;
    const ushort_t* eF1T  = WT + 1310720;     // 2048 x 512
    const ushort_t* eF2T  = WT + 2359296;     // 512 x 2048
    const ushort_t* cWqT  = WT + 3407872;
    const ushort_t* cKV   = WT + 3670016;     // 1024 x 512
    const ushort_t* cWoT  = WT + 4194304;
    const ushort_t* cF1T  = WT + 4456448;
    const ushort_t* cF2T  = WT + 5505024;

    struct WMap { int src; long long dst; int K, N; };
    const WMap wm[13] = {
        {2,  0,       512, 512},   // eWin
        {3,  262144,  512, 512},   // eWq  -> WQKVe rows 0-511
        {4,  524288,  512, 512},   // eWk  -> rows 512-1023
        {5,  786432,  512, 512},   // eWv  -> rows 1024-1535
        {6,  1048576, 512, 512},   // eWo
        {9,  1310720, 512, 2048},  // eF1
        {10, 2359296, 2048, 512},  // eF2
        {13, 3407872, 512, 512},   // cWq
        {14, 3670016, 512, 512},   // cWk -> cKV rows 0-511
        {15, 3932160, 512, 512},   // cWv -> rows 512-1023
        {16, 4194304, 512, 512},   // cWo
        {19, 4456448, 512, 2048},  // cF1
        {20, 5505024, 2048, 512},  // cF2
    };

    cvt_k<<<12800, 256, 0, stream>>>(seqs, SEQB, 26214400LL);
    for (int w = 0; w < 13; ++w) {
        dim3 g(wm[w].N / 32, wm[w].K / 32);
        wtrans_k<<<g, 256, 0, stream>>>((const float*)d_in[wm[w].src],
                                        WT + wm[w].dst, wm[w].K, wm[w].N);
    }
    lens_k<<<4, 256, 0, stream>>>(ends, lens);

    auto gemmL = [&](const ushort_t* A, int agrp, long long astr, const ushort_t* Bt,
                     ushort_t* C, int M, int N, int K, int relu) {
        dim3 g(N / 128, M / 128);
        mfma_gemm<128, 128, 2, 2><<<g, 256, 0, stream>>>(A, agrp, astr, Bt, C, M, N, K, relu);
    };
    auto gemmS = [&](const ushort_t* A, int agrp, long long astr, const ushort_t* Bt,
                     ushort_t* C, int M, int N, int K, int relu) {
        dim3 g(N / 128, M / 64);
        mfma_gemm<64, 128, 2, 2><<<g, 256, 0, stream>>>(A, agrp, astr, Bt, C, M, N, K, relu);
    };

    // ---------------- Phase 1: all encoders, chunks of G segments ----------
    const int Mc = NB * G * SEGL;   // 25600 (G=8) or 12800 (G=4)
    for (int c = 0; c < NT / G; ++c) {
        const int t0 = c * G;
        const ushort_t* Abase = SEQB + (long long)t0 * SEGL * DMODEL;
        ushort_t* ENCc = ENC + (long long)t0 * SEGL * DMODEL;
        gemmL(Abase, G * SEGL, SEQROW, eWinT, BUF0, Mc, 512, 512, 0);
        gemmL(BUF0, Mc, 0, WQKVe, QKV, Mc, 1536, 512, 0);
        attn_mfma_k<<<NB * G * NHEAD, 256, 0, stream>>>(
            QKV, 50LL * 1536, 1536, QKV + 512, QKV + 1024, 50LL * 1536, 1536,
            BUF4, lens, G, t0);
        gemmL(BUF4, Mc, 0, eWoT, BUF1, Mc, 512, 512, 0);
        add_ln_k<false><<<Mc / 4, 256, 0, stream>>>(BUF0, Mc, 0, BUF1, eG1, eB1,
                                                    BUF2, Mc, 0, Mc);
        gemmL(BUF2, Mc, 0, eF1T, MID, Mc, 2048, 512, 1);
        gemmL(MID, Mc, 0, eF2T, BUF1, Mc, 512, 2048, 0);
        add_ln_k<false><<<Mc / 4, 256, 0, stream>>>(BUF2, Mc, 0, BUF1, eG2, eB2,
                                                    ENCc, G * SEGL, SEQROW, Mc);
    }

    // Batched Q projections for ALL phase-2 steps: rows m=(b, t-1, s), t=1..15
    gemmL(ENC + 25600, 750, SEQROW, cWqT, QALL, 48000, 512, 512, 0);

    // ---------------- Phase 2: 15 sequential connection steps ----------------
    const int Ms = NB * SEGL;   // 3200
    for (int t = 1; t < NT; ++t) {
        const ushort_t* currA = ENC + (long long)t * SEGL * DMODEL; // grouped (50, SEQROW)
        const ushort_t* prevA; int pg; long long ps;
        if (t == 1) { prevA = ENC;  pg = SEGL; ps = SEQROW; }
        else        { prevA = OUTB; pg = Ms;   ps = 0; }
        gemmS(prevA, pg, ps, cKV, QKV, Ms, 1024, 512, 0);          // fused KV
        attn_mfma_k<<<NB * NHEAD, 256, 0, stream>>>(
            QALL + (long long)(t - 1) * 25600, 750LL * 512, 512,
            QKV, QKV + 512, 50LL * 1024, 1024,
            BUF4, nullptr, 1, 0);
        gemmS(BUF4, Ms, 0, cWoT, BUF0, Ms, 512, 512, 0);
        add_ln_k<false><<<Ms / 4, 256, 0, stream>>>(currA, SEGL, SEQROW, BUF0, cG1, cB1,
                                                    BUF2, Ms, 0, Ms);
        gemmS(BUF2, Ms, 0, cF1T, MID, Ms, 2048, 512, 1);
        gemmS(MID, Ms, 0, cF2T, BUF0, Ms, 512, 2048, 0);
        if (t == NT - 1)
            add_ln_k<true><<<Ms / 4, 256, 0, stream>>>(BUF2, Ms, 0, BUF0, cG2, cB2,
                                                       out, Ms, 0, Ms);
        else
            add_ln_k<false><<<Ms / 4, 256, 0, stream>>>(BUF2, Ms, 0, BUF0, cG2, cB2,
                                                        OUTB, Ms, 0, Ms);
    }
}